// Round 6
// baseline (173.153 us; speedup 1.0000x reference)
//
#include <hip/hip_runtime.h>
#include <hip/hip_bf16.h>
#include <math.h>

#define NITEMS 100000
#define NUSERS 16384
#define GCN 128
#define GEO 32
#define HIDD 256
#define TD 128
#define RK 50
#define NT_I (NITEMS / 32)   // 3125 item tiles
#define GRID_I 512

typedef unsigned int uint;
typedef unsigned short ushort;
typedef __bf16 bf16x8 __attribute__((ext_vector_type(8)));
typedef float f32x4 __attribute__((ext_vector_type(4)));

__device__ __forceinline__ ushort bfb(float x) {
  union { __hip_bfloat16 b; ushort u; } t; t.b = __float2bfloat16(x); return t.u;
}
__device__ __forceinline__ uint packbf2(float a, float b) {
  return (uint)bfb(a) | ((uint)bfb(b) << 16);
}
__device__ __forceinline__ float bflo(uint d) { return __uint_as_float(d << 16); }
__device__ __forceinline__ float bfhi(uint d) { return __uint_as_float(d & 0xffff0000u); }

union U4B { uint4 u; bf16x8 b; };
__device__ __forceinline__ bf16x8 ldfrag(const ushort* p) { U4B t; t.u = *(const uint4*)p; return t.b; }
__device__ __forceinline__ bf16x8 pack8c(float4 a0, float4 a1) {
  bf16x8 r;
  r[0] = (__bf16)a0.x; r[1] = (__bf16)a0.y; r[2] = (__bf16)a0.z; r[3] = (__bf16)a0.w;
  r[4] = (__bf16)a1.x; r[5] = (__bf16)a1.y; r[6] = (__bf16)a1.z; r[7] = (__bf16)a1.w;
  return r;
}

// ============ prep: weight bf16 convert (chunk-major [K/32][N][32]) + Wqk fold ============
__global__ __launch_bounds__(256) void prep_all(
    const float* __restrict__ Wi1, const float* __restrict__ Wi2,
    const float* __restrict__ Wu1, const float* __restrict__ Wu2,
    const float* __restrict__ Wq, const float* __restrict__ Wk,
    const float* __restrict__ bq,
    ushort* __restrict__ Wi1P, ushort* __restrict__ Wi2P,
    ushort* __restrict__ Wu1P, ushort* __restrict__ Wu2P,
    float* __restrict__ WqkS, float* __restrict__ bqk)
{
  int id = blockIdx.x * 256 + threadIdx.x;
  if (id < 40960) {                       // Wi1 [160][256]
    int k = id >> 8, c = id & 255;
    Wi1P[(k >> 5) * 8192 + c * 32 + (k & 31)] = bfb(Wi1[id]);
  } else if (id < 73728) {                // Wi2 [256][128]
    int i = id - 40960; int k = i >> 7, c = i & 127;
    Wi2P[(k >> 5) * 4096 + c * 32 + (k & 31)] = bfb(Wi2[i]);
  } else if (id < 139264) {               // Wu1 [256][256]
    int i = id - 73728; int k = i >> 8, c = i & 255;
    Wu1P[(k >> 5) * 8192 + c * 32 + (k & 31)] = bfb(Wu1[i]);
  } else if (id < 172032) {               // Wu2 [256][128]
    int i = id - 139264; int k = i >> 7, c = i & 127;
    Wu2P[(k >> 5) * 4096 + c * 32 + (k & 31)] = bfb(Wu2[i]);
  } else if (id < 188416) {               // WqkS[g][s] = Wq[g,:].Wk[s,:]
    int i = id - 172032; int g = i >> 7, s = i & 127;
    float acc = 0.f;
    for (int t = 0; t < 128; t += 4) {
      float4 a = *(const float4*)(Wq + g * 128 + t);
      float4 b = *(const float4*)(Wk + s * 128 + t);
      acc += a.x * b.x + a.y * b.y + a.z * b.z + a.w * b.w;
    }
    WqkS[g * 128 + s] = acc;
  } else if (id < 188544) {               // bqk[s] = bq.Wk[s,:]
    int s = id - 188416;
    float acc = 0.f;
    for (int t = 0; t < 128; t += 4) {
      float4 a = *(const float4*)(bq + t);
      float4 b = *(const float4*)(Wk + s * 128 + t);
      acc += a.x * b.x + a.y * b.y + a.z * b.z + a.w * b.w;
    }
    bqk[s] = acc;
  }
}

// ======================= ITEM tower: persistent, register-resident weights =======================
// 512 blocks x ~6 tiles of 32 rows. All weights (144 VGPR) loaded once per block.
// A tile double-buffered in LDS (coalesced f32 stage, padded stride 132).
__global__ __launch_bounds__(256, 2) void item_mlp(
    const float* __restrict__ gcn_item, const float* __restrict__ feat,
    const float* __restrict__ Wg, const float* __restrict__ bg,
    const ushort* __restrict__ W1P, const float* __restrict__ b1,
    const ushort* __restrict__ W2P, const float* __restrict__ b2,
    float* __restrict__ outp, ushort* __restrict__ outb)
{
  __shared__ __align__(16) float  s_x[2][32 * 132];   // A dbuf (f32, padded)
  __shared__ __align__(16) ushort s_h[32 * 264];      // hidden tile (bf16)
  __shared__ float s_red[32 * 4];
  __shared__ float s_inv[32];

  const int tid = threadIdx.x;
  const int wid = tid >> 6, lane = tid & 63, g = lane >> 4, q = lane & 15;

  // ---- load ALL weights into registers (once per block)
  bf16x8 wb1[5][4], wb2[8][2];
  #pragma unroll
  for (int kb = 0; kb < 5; ++kb)
    #pragma unroll
    for (int cf = 0; cf < 4; ++cf)
      wb1[kb][cf] = ldfrag(W1P + kb * 8192 + (wid * 64 + cf * 16 + q) * 32 + g * 8);
  #pragma unroll
  for (int kb = 0; kb < 8; ++kb)
    #pragma unroll
    for (int cf = 0; cf < 2; ++cf)
      wb2[kb][cf] = ldfrag(W2P + kb * 4096 + (wid * 32 + cf * 16 + q) * 32 + g * 8);

  float bv1[4], bv2[2];
  #pragma unroll
  for (int cf = 0; cf < 4; ++cf) bv1[cf] = b1[wid * 64 + cf * 16 + q];
  #pragma unroll
  for (int cf = 0; cf < 2; ++cf) bv2[cf] = b2[wid * 32 + cf * 16 + q];

  // geo weights for this lane's 8 columns (loop-invariant)
  const float4 w0a = *(const float4*)(Wg + g * 8),      w0b = *(const float4*)(Wg + g * 8 + 4);
  const float4 w1a = *(const float4*)(Wg + 32 + g * 8), w1b = *(const float4*)(Wg + 32 + g * 8 + 4);
  const float4 ba  = *(const float4*)(bg + g * 8),      bb = *(const float4*)(bg + g * 8 + 4);

  // ---- prologue: stage tile(bid) into buf 0
  float4 stg[4];
  float2 fc0, fc1, fn0, fn1;
  {
    const int i0 = blockIdx.x * 32;
    #pragma unroll
    for (int i = 0; i < 4; ++i) {
      int f = i * 256 + tid, row = f >> 5, c4 = (f & 31) * 4;
      stg[i] = *(const float4*)(gcn_item + (size_t)(i0 + row) * GCN + c4);
    }
    fc0 = *(const float2*)(feat + 2 * (size_t)(i0 + q));
    fc1 = *(const float2*)(feat + 2 * (size_t)(i0 + q + 16));
    #pragma unroll
    for (int i = 0; i < 4; ++i) {
      int f = i * 256 + tid, row = f >> 5, c4 = (f & 31) * 4;
      *(float4*)(&s_x[0][row * 132 + c4]) = stg[i];
    }
  }

  int cur = 0;
  for (int t = blockIdx.x; t < NT_I; t += GRID_I) {
    const int tn = t + GRID_I;
    const bool hn = tn < NT_I;
    if (hn) {   // issue next tile's loads NOW; they complete under GEMM1
      const int i0n = tn * 32;
      #pragma unroll
      for (int i = 0; i < 4; ++i) {
        int f = i * 256 + tid, row = f >> 5, c4 = (f & 31) * 4;
        stg[i] = *(const float4*)(gcn_item + (size_t)(i0n + row) * GCN + c4);
      }
      fn0 = *(const float2*)(feat + 2 * (size_t)(i0n + q));
      fn1 = *(const float2*)(feat + 2 * (size_t)(i0n + q + 16));
    }
    __syncthreads();   // tile t visible in s_x[cur]

    // ---- GEMM1: [32 x 160] @ [160 x 256], B in registers
    f32x4 acc[2][4];
    #pragma unroll
    for (int cf = 0; cf < 4; ++cf) {
      f32x4 tv = {bv1[cf], bv1[cf], bv1[cf], bv1[cf]};
      acc[0][cf] = tv; acc[1][cf] = tv;
    }
    #pragma unroll
    for (int kb = 0; kb < 5; ++kb) {
      bf16x8 af[2];
      if (kb == 0) {
        // geo chunk in-register: relu(f0*Wg[c] + f1*Wg[32+c] + bg[c])
        float4 lo, hi;
        lo.x = fmaxf(fmaf(fc0.x, w0a.x, fmaf(fc0.y, w1a.x, ba.x)), 0.f);
        lo.y = fmaxf(fmaf(fc0.x, w0a.y, fmaf(fc0.y, w1a.y, ba.y)), 0.f);
        lo.z = fmaxf(fmaf(fc0.x, w0a.z, fmaf(fc0.y, w1a.z, ba.z)), 0.f);
        lo.w = fmaxf(fmaf(fc0.x, w0a.w, fmaf(fc0.y, w1a.w, ba.w)), 0.f);
        hi.x = fmaxf(fmaf(fc0.x, w0b.x, fmaf(fc0.y, w1b.x, bb.x)), 0.f);
        hi.y = fmaxf(fmaf(fc0.x, w0b.y, fmaf(fc0.y, w1b.y, bb.y)), 0.f);
        hi.z = fmaxf(fmaf(fc0.x, w0b.z, fmaf(fc0.y, w1b.z, bb.z)), 0.f);
        hi.w = fmaxf(fmaf(fc0.x, w0b.w, fmaf(fc0.y, w1b.w, bb.w)), 0.f);
        af[0] = pack8c(lo, hi);
        lo.x = fmaxf(fmaf(fc1.x, w0a.x, fmaf(fc1.y, w1a.x, ba.x)), 0.f);
        lo.y = fmaxf(fmaf(fc1.x, w0a.y, fmaf(fc1.y, w1a.y, ba.y)), 0.f);
        lo.z = fmaxf(fmaf(fc1.x, w0a.z, fmaf(fc1.y, w1a.z, ba.z)), 0.f);
        lo.w = fmaxf(fmaf(fc1.x, w0a.w, fmaf(fc1.y, w1a.w, ba.w)), 0.f);
        hi.x = fmaxf(fmaf(fc1.x, w0b.x, fmaf(fc1.y, w1b.x, bb.x)), 0.f);
        hi.y = fmaxf(fmaf(fc1.x, w0b.y, fmaf(fc1.y, w1b.y, bb.y)), 0.f);
        hi.z = fmaxf(fmaf(fc1.x, w0b.z, fmaf(fc1.y, w1b.z, bb.z)), 0.f);
        hi.w = fmaxf(fmaf(fc1.x, w0b.w, fmaf(fc1.y, w1b.w, bb.w)), 0.f);
        af[1] = pack8c(lo, hi);
      } else {
        #pragma unroll
        for (int rf = 0; rf < 2; ++rf) {
          const float* rp = &s_x[cur][(q + 16 * rf) * 132 + (kb - 1) * 32 + g * 8];
          af[rf] = pack8c(*(const float4*)rp, *(const float4*)(rp + 4));
        }
      }
      #pragma unroll
      for (int rf = 0; rf < 2; ++rf)
        #pragma unroll
        for (int cf = 0; cf < 4; ++cf)
          acc[rf][cf] = __builtin_amdgcn_mfma_f32_16x16x32_bf16(af[rf], wb1[kb][cf], acc[rf][cf], 0, 0, 0);
    }

    // ---- write next tile into the other buffer (loads already in flight)
    if (hn) {
      #pragma unroll
      for (int i = 0; i < 4; ++i) {
        int f = i * 256 + tid, row = f >> 5, c4 = (f & 31) * 4;
        *(float4*)(&s_x[cur ^ 1][row * 132 + c4]) = stg[i];
      }
    }

    // ---- relu(hidden) -> s_h
    #pragma unroll
    for (int rf = 0; rf < 2; ++rf)
      #pragma unroll
      for (int cf = 0; cf < 4; ++cf)
        #pragma unroll
        for (int e = 0; e < 4; ++e)
          s_h[(16 * rf + 4 * g + e) * 264 + wid * 64 + cf * 16 + q] = bfb(fmaxf(acc[rf][cf][e], 0.f));
    __syncthreads();   // hidden ready

    // ---- GEMM2: [32 x 256] @ [256 x 128], B in registers
    f32x4 acc2[2][2];
    #pragma unroll
    for (int cf = 0; cf < 2; ++cf) {
      f32x4 tv = {bv2[cf], bv2[cf], bv2[cf], bv2[cf]};
      acc2[0][cf] = tv; acc2[1][cf] = tv;
    }
    #pragma unroll
    for (int kb = 0; kb < 8; ++kb) {
      bf16x8 af[2];
      #pragma unroll
      for (int rf = 0; rf < 2; ++rf) af[rf] = ldfrag(&s_h[(16 * rf + q) * 264 + kb * 32 + g * 8]);
      #pragma unroll
      for (int rf = 0; rf < 2; ++rf)
        #pragma unroll
        for (int cf = 0; cf < 2; ++cf)
          acc2[rf][cf] = __builtin_amdgcn_mfma_f32_16x16x32_bf16(af[rf], wb2[kb][cf], acc2[rf][cf], 0, 0, 0);
    }

    // ---- row L2-norm
    #pragma unroll
    for (int rf = 0; rf < 2; ++rf) {
      #pragma unroll
      for (int e = 0; e < 4; ++e) {
        float p = acc2[rf][0][e] * acc2[rf][0][e] + acc2[rf][1][e] * acc2[rf][1][e];
        p += __shfl_xor(p, 1, 16); p += __shfl_xor(p, 2, 16);
        p += __shfl_xor(p, 4, 16); p += __shfl_xor(p, 8, 16);
        if (q == 0) s_red[(16 * rf + 4 * g + e) * 4 + wid] = p;
      }
    }
    __syncthreads();
    if (tid < 32) {
      float s = s_red[tid * 4] + s_red[tid * 4 + 1] + s_red[tid * 4 + 2] + s_red[tid * 4 + 3];
      s_inv[tid] = 1.f / fmaxf(sqrtf(s), 1e-12f);
    }
    __syncthreads();

    // ---- store f32 out + bf16 copy
    {
      const int i0 = t * 32;
      #pragma unroll
      for (int rf = 0; rf < 2; ++rf) {
        #pragma unroll
        for (int e = 0; e < 4; ++e) {
          int row = 16 * rf + 4 * g + e;
          float sc = s_inv[row];
          #pragma unroll
          for (int cf = 0; cf < 2; ++cf) {
            float v = acc2[rf][cf][e] * sc;
            outp[(size_t)(i0 + row) * TD + wid * 32 + cf * 16 + q] = v;
            outb[(size_t)(i0 + row) * TD + wid * 32 + cf * 16 + q] = bfb(v);
          }
        }
      }
    }
    fc0 = fn0; fc1 = fn1;
    cur ^= 1;
  }
}

// ======================= USER tower: 32 users/block, GEMM1 weights register-resident =======================
__global__ __launch_bounds__(256, 2) void user_mlp(
    const float* __restrict__ gcn_user, const ushort* __restrict__ repB,
    const ushort* __restrict__ W1P, const float* __restrict__ b1,
    const ushort* __restrict__ W2P, const float* __restrict__ b2,
    float* __restrict__ outp)
{
  __shared__ __align__(16) ushort s_h[32 * 264];
  __shared__ float s_red[32 * 4];
  __shared__ float s_inv[32];

  const int tid = threadIdx.x;
  const int wid = tid >> 6, lane = tid & 63, g = lane >> 4, q = lane & 15;
  const int i0 = blockIdx.x * 32;

  // GEMM1 weights resident (128 VGPR)
  bf16x8 wb1[8][4];
  #pragma unroll
  for (int kb = 0; kb < 8; ++kb)
    #pragma unroll
    for (int cf = 0; cf < 4; ++cf)
      wb1[kb][cf] = ldfrag(W1P + kb * 8192 + (wid * 64 + cf * 16 + q) * 32 + g * 8);

  // ---- GEMM1: [32 x 256] @ [256 x 256]
  f32x4 acc[2][4];
  #pragma unroll
  for (int cf = 0; cf < 4; ++cf) {
    float bv = b1[wid * 64 + cf * 16 + q];
    f32x4 tv = {bv, bv, bv, bv};
    acc[0][cf] = tv; acc[1][cf] = tv;
  }
  #pragma unroll
  for (int kb = 0; kb < 8; ++kb) {
    bf16x8 af[2];
    if (kb < 4) {
      #pragma unroll
      for (int rf = 0; rf < 2; ++rf) {
        const float* rp = gcn_user + (size_t)(i0 + q + 16 * rf) * GCN + kb * 32 + g * 8;
        af[rf] = pack8c(*(const float4*)rp, *(const float4*)(rp + 4));
      }
    } else {
      #pragma unroll
      for (int rf = 0; rf < 2; ++rf) {
        U4B t;
        t.u = *(const uint4*)(repB + (size_t)(i0 + q + 16 * rf) * TD + (kb - 4) * 32 + g * 8);
        af[rf] = t.b;
      }
    }
    #pragma unroll
    for (int rf = 0; rf < 2; ++rf)
      #pragma unroll
      for (int cf = 0; cf < 4; ++cf)
        acc[rf][cf] = __builtin_amdgcn_mfma_f32_16x16x32_bf16(af[rf], wb1[kb][cf], acc[rf][cf], 0, 0, 0);
  }

  // ---- relu(hidden) -> s_h
  #pragma unroll
  for (int rf = 0; rf < 2; ++rf)
    #pragma unroll
    for (int cf = 0; cf < 4; ++cf)
      #pragma unroll
      for (int e = 0; e < 4; ++e)
        s_h[(16 * rf + 4 * g + e) * 264 + wid * 64 + cf * 16 + q] = bfb(fmaxf(acc[rf][cf][e], 0.f));
  __syncthreads();

  // ---- GEMM2: [32 x 256] @ [256 x 128], B streamed from L2
  f32x4 acc2[2][2];
  #pragma unroll
  for (int cf = 0; cf < 2; ++cf) {
    float bv = b2[wid * 32 + cf * 16 + q];
    f32x4 tv = {bv, bv, bv, bv};
    acc2[0][cf] = tv; acc2[1][cf] = tv;
  }
  {
    const ushort* bbase2 = W2P + (wid * 32 + q) * 32 + g * 8;
    #pragma unroll
    for (int kb = 0; kb < 8; ++kb) {
      bf16x8 af[2], bf2[2];
      #pragma unroll
      for (int rf = 0; rf < 2; ++rf) af[rf] = ldfrag(&s_h[(16 * rf + q) * 264 + kb * 32 + g * 8]);
      #pragma unroll
      for (int cf = 0; cf < 2; ++cf) bf2[cf] = ldfrag(bbase2 + kb * 4096 + cf * 512);
      #pragma unroll
      for (int rf = 0; rf < 2; ++rf)
        #pragma unroll
        for (int cf = 0; cf < 2; ++cf)
          acc2[rf][cf] = __builtin_amdgcn_mfma_f32_16x16x32_bf16(af[rf], bf2[cf], acc2[rf][cf], 0, 0, 0);
    }
  }

  // ---- row L2-norm + store
  #pragma unroll
  for (int rf = 0; rf < 2; ++rf) {
    #pragma unroll
    for (int e = 0; e < 4; ++e) {
      float p = acc2[rf][0][e] * acc2[rf][0][e] + acc2[rf][1][e] * acc2[rf][1][e];
      p += __shfl_xor(p, 1, 16); p += __shfl_xor(p, 2, 16);
      p += __shfl_xor(p, 4, 16); p += __shfl_xor(p, 8, 16);
      if (q == 0) s_red[(16 * rf + 4 * g + e) * 4 + wid] = p;
    }
  }
  __syncthreads();
  if (tid < 32) {
    float s = s_red[tid * 4] + s_red[tid * 4 + 1] + s_red[tid * 4 + 2] + s_red[tid * 4 + 3];
    s_inv[tid] = 1.f / fmaxf(sqrtf(s), 1e-12f);
  }
  __syncthreads();
  #pragma unroll
  for (int rf = 0; rf < 2; ++rf) {
    #pragma unroll
    for (int e = 0; e < 4; ++e) {
      int row = 16 * rf + 4 * g + e;
      float sc = s_inv[row];
      #pragma unroll
      for (int cf = 0; cf < 2; ++cf)
        outp[(size_t)(i0 + row) * TD + wid * 32 + cf * 16 + q] = acc2[rf][cf][e] * sc;
    }
  }
}

// ======================= qt = gue @ WqkS + bqk =======================
__global__ __launch_bounds__(256) void qt_kernel(
    const float* __restrict__ gcn_user, const float* __restrict__ WqkS,
    const float* __restrict__ bqk, float* __restrict__ qt)
{
  __shared__ float s_gue[16 * 132];
  const int tid = threadIdx.x;
  const int u0 = blockIdx.x * 16;
  #pragma unroll
  for (int r = 0; r < 8; ++r) {
    int lin = r * 256 + tid;
    int u = lin >> 7, c = lin & 127;
    s_gue[u * 132 + c] = gcn_user[(size_t)(u0 + u) * GCN + c];
  }
  __syncthreads();
  const int ul = tid >> 4, tx = tid & 15, c0 = tx * 8;
  float a[8];
  { float4 b4 = *(const float4*)(bqk + c0); float4 b5 = *(const float4*)(bqk + c0 + 4);
    a[0]=b4.x; a[1]=b4.y; a[2]=b4.z; a[3]=b4.w; a[4]=b5.x; a[5]=b5.y; a[6]=b5.z; a[7]=b5.w; }
  for (int g = 0; g < 128; ++g) {
    float x = s_gue[ul * 132 + g];
    float4 w4 = *(const float4*)(WqkS + g * 128 + c0);
    float4 w5 = *(const float4*)(WqkS + g * 128 + c0 + 4);
    a[0] = fmaf(x, w4.x, a[0]); a[1] = fmaf(x, w4.y, a[1]);
    a[2] = fmaf(x, w4.z, a[2]); a[3] = fmaf(x, w4.w, a[3]);
    a[4] = fmaf(x, w5.x, a[4]); a[5] = fmaf(x, w5.y, a[5]);
    a[6] = fmaf(x, w5.z, a[6]); a[7] = fmaf(x, w5.w, a[7]);
  }
  float* op = qt + (size_t)(u0 + ul) * TD + c0;
  *(float4*)op = make_float4(a[0], a[1], a[2], a[3]);
  *(float4*)(op + 4) = make_float4(a[4], a[5], a[6], a[7]);
}

// ======================= attention: one wave per user, single-pass =======================
__global__ __launch_bounds__(256) void attn_kernel(
    const int* __restrict__ user_items, const float* __restrict__ qt,
    const ushort* __restrict__ itemB, ushort* __restrict__ repB)
{
  __shared__ int s_idx[4][52];
  const int tid = threadIdx.x;
  const int wid = tid >> 6, lane = tid & 63, g = lane >> 4, q = lane & 15;
  const int u = blockIdx.x * 4 + wid;
  const int c0 = q * 8;

  if (lane < 52) s_idx[wid][lane] = (lane < 50) ? user_items[(size_t)u * RK + lane] : 0;
  float qv[8];
  { float4 a = *(const float4*)(qt + (size_t)u * TD + c0);
    float4 b = *(const float4*)(qt + (size_t)u * TD + c0 + 4);
    qv[0]=a.x; qv[1]=a.y; qv[2]=a.z; qv[3]=a.w; qv[4]=b.x; qv[5]=b.y; qv[6]=b.z; qv[7]=b.w; }
  // s_idx is wave-local: no block barrier needed

  uint4 h[13]; float sc[13];
  #pragma unroll
  for (int i = 0; i < 13; ++i) {
    int j = 4 * i + g;
    int idx = s_idx[wid][j];
    h[i] = *(const uint4*)(itemB + (size_t)idx * TD + c0);
    float p = bflo(h[i].x) * qv[0] + bfhi(h[i].x) * qv[1]
            + bflo(h[i].y) * qv[2] + bfhi(h[i].y) * qv[3]
            + bflo(h[i].z) * qv[4] + bfhi(h[i].z) * qv[5]
            + bflo(h[i].w) * qv[6] + bfhi(h[i].w) * qv[7];
    p += __shfl_xor(p, 1, 16); p += __shfl_xor(p, 2, 16);
    p += __shfl_xor(p, 4, 16); p += __shfl_xor(p, 8, 16);
    sc[i] = (j < RK) ? p : -3.0e38f;
  }
  float m = sc[0];
  #pragma unroll
  for (int i = 1; i < 13; ++i) m = fmaxf(m, sc[i]);
  m = fmaxf(m, __shfl_xor(m, 16, 64));
  m = fmaxf(m, __shfl_xor(m, 32, 64));
  float ssum = 0.f;
  #pragma unroll
  for (int i = 0; i < 13; ++i) { sc[i] = __expf(sc[i] - m); ssum += sc[i]; }
  ssum += __shfl_xor(ssum, 16, 64);
  ssum += __shfl_xor(ssum, 32, 64);
  const float inv = 1.f / ssum;
  float rep[8] = {0, 0, 0, 0, 0, 0, 0, 0};
  #pragma unroll
  for (int i = 0; i < 13; ++i) {
    float a = sc[i] * inv;
    rep[0] = fmaf(a, bflo(h[i].x), rep[0]); rep[1] = fmaf(a, bfhi(h[i].x), rep[1]);
    rep[2] = fmaf(a, bflo(h[i].y), rep[2]); rep[3] = fmaf(a, bfhi(h[i].y), rep[3]);
    rep[4] = fmaf(a, bflo(h[i].z), rep[4]); rep[5] = fmaf(a, bfhi(h[i].z), rep[5]);
    rep[6] = fmaf(a, bflo(h[i].w), rep[6]); rep[7] = fmaf(a, bfhi(h[i].w), rep[7]);
  }
  #pragma unroll
  for (int c = 0; c < 8; ++c) {
    rep[c] += __shfl_xor(rep[c], 16, 64);
    rep[c] += __shfl_xor(rep[c], 32, 64);
  }
  if (g == 0) {
    uint4 o;
    o.x = packbf2(rep[0], rep[1]); o.y = packbf2(rep[2], rep[3]);
    o.z = packbf2(rep[4], rep[5]); o.w = packbf2(rep[6], rep[7]);
    *(uint4*)(repB + (size_t)u * TD + c0) = o;
  }
}

extern "C" void kernel_launch(void* const* d_in, const int* in_sizes, int n_in,
                              void* d_out, int out_size, void* d_ws, size_t ws_size,
                              hipStream_t stream) {
  const float* item_feat  = (const float*)d_in[0];
  const float* gcn_item   = (const float*)d_in[1];
  const float* gcn_user   = (const float*)d_in[2];
  const int*   user_items = (const int*)  d_in[3];
  const float* Wg  = (const float*)d_in[4];
  const float* bg  = (const float*)d_in[5];
  const float* Wi1 = (const float*)d_in[6];
  const float* bi1 = (const float*)d_in[7];
  const float* Wi2 = (const float*)d_in[8];
  const float* bi2 = (const float*)d_in[9];
  const float* Wq  = (const float*)d_in[10];
  const float* bq  = (const float*)d_in[11];
  const float* Wk  = (const float*)d_in[12];
  // d_in[13] = bk: softmax-invariant, dropped
  const float* Wu1 = (const float*)d_in[14];
  const float* bu1 = (const float*)d_in[15];
  const float* Wu2 = (const float*)d_in[16];
  const float* bu2 = (const float*)d_in[17];
  float* out = (float*)d_out;

  // workspace layout (bytes): ~34.3 MB total
  char* ws = (char*)d_ws;
  ushort* Wi1P  = (ushort*)(ws + 0);         // 5*256*32*2  =  81920
  ushort* Wi2P  = (ushort*)(ws + 81920);     // 8*128*32*2  =  65536
  ushort* Wu1P  = (ushort*)(ws + 147456);    // 8*256*32*2  = 131072
  ushort* Wu2P  = (ushort*)(ws + 278528);    // 8*128*32*2  =  65536
  float*  WqkS  = (float*) (ws + 344064);    // 128*128*4   =  65536
  float*  bqk   = (float*) (ws + 409600);    // 128*4       =    512
  float*  qtb   = (float*) (ws + 410112);    // 16384*128*4 = 8388608
  ushort* itemB = (ushort*)(ws + 8798720);   // 100000*128*2 = 25600000
  ushort* repB  = (ushort*)(ws + 34398720);  // 16384*128*2 = 4194304

  prep_all<<<737, 256, 0, stream>>>(Wi1, Wi2, Wu1, Wu2, Wq, Wk, bq,
                                    Wi1P, Wi2P, Wu1P, Wu2P, WqkS, bqk);
  qt_kernel<<<NUSERS / 16, 256, 0, stream>>>(gcn_user, WqkS, bqk, qtb);
  item_mlp<<<GRID_I, 256, 0, stream>>>(
      gcn_item, item_feat, Wg, bg, Wi1P, bi1, Wi2P, bi2, out, itemB);
  attn_kernel<<<NUSERS / 4, 256, 0, stream>>>(user_items, qtb, itemB, repB);
  user_mlp<<<NUSERS / 32, 256, 0, stream>>>(
      gcn_user, repB, Wu1P, bu1, Wu2P, bu2, out + (size_t)NITEMS * TD);
}

// Round 7
// 172.763 us; speedup vs baseline: 1.0023x; 1.0023x over previous
//
#include <hip/hip_runtime.h>
#include <hip/hip_bf16.h>
#include <math.h>

#define NITEMS 100000
#define NUSERS 16384
#define GCN 128
#define GEO 32
#define HIDD 256
#define TD 128
#define RK 50

typedef unsigned int uint;
typedef unsigned short ushort;
typedef __bf16 bf16x8 __attribute__((ext_vector_type(8)));
typedef float f32x4 __attribute__((ext_vector_type(4)));

__device__ __forceinline__ ushort bfb(float x) {
  union { __hip_bfloat16 b; ushort u; } t; t.b = __float2bfloat16(x); return t.u;
}
__device__ __forceinline__ uint packbf2(float a, float b) {
  return (uint)bfb(a) | ((uint)bfb(b) << 16);
}

union U4B { uint4 u; bf16x8 b; };
__device__ __forceinline__ bf16x8 ldfrag(const ushort* p) { U4B t; t.u = *(const uint4*)p; return t.b; }
__device__ __forceinline__ bf16x8 pack8c(float4 a0, float4 a1) {
  bf16x8 r;
  r[0] = (__bf16)a0.x; r[1] = (__bf16)a0.y; r[2] = (__bf16)a0.z; r[3] = (__bf16)a0.w;
  r[4] = (__bf16)a1.x; r[5] = (__bf16)a1.y; r[6] = (__bf16)a1.z; r[7] = (__bf16)a1.w;
  return r;
}

// ============ prep: weight bf16 convert (chunk-major [K/32][N][32]) + Wqk fold
// ============ + gcn_item f32->bf16 (padded to 100032 rows) ============
__global__ __launch_bounds__(256) void prep_all(
    const float* __restrict__ Wi1, const float* __restrict__ Wi2,
    const float* __restrict__ Wu1, const float* __restrict__ Wu2,
    const float* __restrict__ Wq, const float* __restrict__ Wk,
    const float* __restrict__ bq, const float* __restrict__ gcn_item,
    ushort* __restrict__ Wi1P, ushort* __restrict__ Wi2P,
    ushort* __restrict__ Wu1P, ushort* __restrict__ Wu2P,
    float* __restrict__ WqkS, float* __restrict__ bqk,
    ushort* __restrict__ gitemB)
{
  int id = blockIdx.x * 256 + threadIdx.x;
  if (id < 40960) {                       // Wi1 [160][256]
    int k = id >> 8, c = id & 255;
    Wi1P[(k >> 5) * 8192 + c * 32 + (k & 31)] = bfb(Wi1[id]);
  } else if (id < 73728) {                // Wi2 [256][128]
    int i = id - 40960; int k = i >> 7, c = i & 127;
    Wi2P[(k >> 5) * 4096 + c * 32 + (k & 31)] = bfb(Wi2[i]);
  } else if (id < 139264) {               // Wu1 [256][256]
    int i = id - 73728; int k = i >> 8, c = i & 255;
    Wu1P[(k >> 5) * 8192 + c * 32 + (k & 31)] = bfb(Wu1[i]);
  } else if (id < 172032) {               // Wu2 [256][128]
    int i = id - 139264; int k = i >> 7, c = i & 127;
    Wu2P[(k >> 5) * 4096 + c * 32 + (k & 31)] = bfb(Wu2[i]);
  } else if (id < 188416) {               // WqkS[g][s] = Wq[g,:].Wk[s,:]
    int i = id - 172032; int g = i >> 7, s = i & 127;
    float acc = 0.f;
    for (int t = 0; t < 128; t += 4) {
      float4 a = *(const float4*)(Wq + g * 128 + t);
      float4 b = *(const float4*)(Wk + s * 128 + t);
      acc += a.x * b.x + a.y * b.y + a.z * b.z + a.w * b.w;
    }
    WqkS[g * 128 + s] = acc;
  } else if (id < 188544) {               // bqk[s] = bq.Wk[s,:]
    int s = id - 188416;
    float acc = 0.f;
    for (int t = 0; t < 128; t += 4) {
      float4 a = *(const float4*)(bq + t);
      float4 b = *(const float4*)(Wk + s * 128 + t);
      acc += a.x * b.x + a.y * b.y + a.z * b.z + a.w * b.w;
    }
    bqk[s] = acc;
  } else if (id < 1788544) {              // gcn_item -> bf16, 8 elems/thread
    size_t base = (size_t)(id - 188544) * 8;
    float4 v0 = *(const float4*)(gcn_item + base);
    float4 v1 = *(const float4*)(gcn_item + base + 4);
    uint4 o;
    o.x = packbf2(v0.x, v0.y); o.y = packbf2(v0.z, v0.w);
    o.z = packbf2(v1.x, v1.y); o.w = packbf2(v1.z, v1.w);
    *(uint4*)(gitemB + base) = o;
  } else if (id < 1789056) {              // zero pad rows 100000..100031
    int t = id - 1788544;
    uint4 z; z.x = 0; z.y = 0; z.z = 0; z.w = 0;
    *(uint4*)(gitemB + (size_t)12800000 + (size_t)t * 8) = z;
  }
}

// ======================= ITEM tower: direct-fragment, single-barrier =======================
// 64 rows/block, 4 waves split N. A-fragments: one uint4/lane from bf16 gitemB
// (geo chunk computed in-register). B streamed from L2 with depth-1 prefetch.
__global__ __launch_bounds__(256, 3) void item_mlp(
    const ushort* __restrict__ gitemB, const float* __restrict__ feat,
    const float* __restrict__ Wg, const float* __restrict__ bg,
    const ushort* __restrict__ W1P, const float* __restrict__ b1,
    const ushort* __restrict__ W2P, const float* __restrict__ b2,
    float* __restrict__ outp)
{
  __shared__ __align__(16) ushort s_h[64 * 264];
  __shared__ float s_red[64 * 4];

  const int tid = threadIdx.x;
  const int wid = tid >> 6, lane = tid & 63, g = lane >> 4, q = lane & 15;
  const int i0 = blockIdx.x * 64;

  // B chunk-0 prefetch
  const ushort* bb1 = W1P + (wid * 64 + q) * 32 + g * 8;
  bf16x8 bcur[4];
  #pragma unroll
  for (int cf = 0; cf < 4; ++cf) bcur[cf] = ldfrag(bb1 + cf * 512);

  // chunk 0 (geo) in-register
  bf16x8 acur[4];
  {
    const float4 w0a = *(const float4*)(Wg + g * 8),      w0b = *(const float4*)(Wg + g * 8 + 4);
    const float4 w1a = *(const float4*)(Wg + 32 + g * 8), w1b = *(const float4*)(Wg + 32 + g * 8 + 4);
    const float4 ba  = *(const float4*)(bg + g * 8),      bb = *(const float4*)(bg + g * 8 + 4);
    #pragma unroll
    for (int rf = 0; rf < 4; ++rf) {
      int row = i0 + q + 16 * rf;
      if (row > NITEMS - 1) row = NITEMS - 1;   // clamp (stores guarded)
      float2 f = *(const float2*)(feat + 2 * (size_t)row);
      float4 lo, hi;
      lo.x = fmaxf(fmaf(f.x, w0a.x, fmaf(f.y, w1a.x, ba.x)), 0.f);
      lo.y = fmaxf(fmaf(f.x, w0a.y, fmaf(f.y, w1a.y, ba.y)), 0.f);
      lo.z = fmaxf(fmaf(f.x, w0a.z, fmaf(f.y, w1a.z, ba.z)), 0.f);
      lo.w = fmaxf(fmaf(f.x, w0a.w, fmaf(f.y, w1a.w, ba.w)), 0.f);
      hi.x = fmaxf(fmaf(f.x, w0b.x, fmaf(f.y, w1b.x, bb.x)), 0.f);
      hi.y = fmaxf(fmaf(f.x, w0b.y, fmaf(f.y, w1b.y, bb.y)), 0.f);
      hi.z = fmaxf(fmaf(f.x, w0b.z, fmaf(f.y, w1b.z, bb.z)), 0.f);
      hi.w = fmaxf(fmaf(f.x, w0b.w, fmaf(f.y, w1b.w, bb.w)), 0.f);
      acur[rf] = pack8c(lo, hi);
    }
  }

  // ---- GEMM1: [64 x 160] @ [160 x 256], depth-1 A+B prefetch, barrier-free
  f32x4 acc[4][4];
  #pragma unroll
  for (int cf = 0; cf < 4; ++cf) {
    float bv = b1[wid * 64 + cf * 16 + q];
    f32x4 t = {bv, bv, bv, bv};
    #pragma unroll
    for (int rf = 0; rf < 4; ++rf) acc[rf][cf] = t;
  }
  #pragma unroll
  for (int kb = 0; kb < 5; ++kb) {
    bf16x8 anxt[4], bnxt[4];
    if (kb < 4) {
      #pragma unroll
      for (int rf = 0; rf < 4; ++rf)   // chunk kb+1 = gcn cols kb*32..
        anxt[rf] = ldfrag(gitemB + (size_t)(i0 + q + 16 * rf) * GCN + kb * 32 + g * 8);
      #pragma unroll
      for (int cf = 0; cf < 4; ++cf) bnxt[cf] = ldfrag(bb1 + (kb + 1) * 8192 + cf * 512);
    }
    #pragma unroll
    for (int rf = 0; rf < 4; ++rf)
      #pragma unroll
      for (int cf = 0; cf < 4; ++cf)
        acc[rf][cf] = __builtin_amdgcn_mfma_f32_16x16x32_bf16(acur[rf], bcur[cf], acc[rf][cf], 0, 0, 0);
    if (kb < 4) {
      #pragma unroll
      for (int rf = 0; rf < 4; ++rf) acur[rf] = anxt[rf];
      #pragma unroll
      for (int cf = 0; cf < 4; ++cf) bcur[cf] = bnxt[cf];
    }
  }

  // GEMM2 chunk-0 B prefetch (issues before the barrier)
  const ushort* bb2 = W2P + (wid * 32 + q) * 32 + g * 8;
  bf16x8 b2cur[2];
  #pragma unroll
  for (int cf = 0; cf < 2; ++cf) b2cur[cf] = ldfrag(bb2 + cf * 512);

  // ---- relu(hidden) -> LDS
  #pragma unroll
  for (int rf = 0; rf < 4; ++rf)
    #pragma unroll
    for (int cf = 0; cf < 4; ++cf)
      #pragma unroll
      for (int e = 0; e < 4; ++e)
        s_h[(16 * rf + 4 * g + e) * 264 + wid * 64 + cf * 16 + q] = bfb(fmaxf(acc[rf][cf][e], 0.f));
  __syncthreads();   // the ONLY pre-GEMM2 barrier

  // ---- GEMM2: [64 x 256] @ [256 x 128], depth-1 B prefetch
  f32x4 acc2[4][2];
  #pragma unroll
  for (int cf = 0; cf < 2; ++cf) {
    float bv = b2[wid * 32 + cf * 16 + q];
    f32x4 t = {bv, bv, bv, bv};
    #pragma unroll
    for (int rf = 0; rf < 4; ++rf) acc2[rf][cf] = t;
  }
  #pragma unroll
  for (int kb = 0; kb < 8; ++kb) {
    bf16x8 bnxt[2];
    if (kb < 7) {
      #pragma unroll
      for (int cf = 0; cf < 2; ++cf) bnxt[cf] = ldfrag(bb2 + (kb + 1) * 4096 + cf * 512);
    }
    bf16x8 af[4];
    #pragma unroll
    for (int rf = 0; rf < 4; ++rf) af[rf] = ldfrag(&s_h[(16 * rf + q) * 264 + kb * 32 + g * 8]);
    #pragma unroll
    for (int rf = 0; rf < 4; ++rf)
      #pragma unroll
      for (int cf = 0; cf < 2; ++cf)
        acc2[rf][cf] = __builtin_amdgcn_mfma_f32_16x16x32_bf16(af[rf], b2cur[cf], acc2[rf][cf], 0, 0, 0);
    if (kb < 7) {
      #pragma unroll
      for (int cf = 0; cf < 2; ++cf) b2cur[cf] = bnxt[cf];
    }
  }

  // ---- row L2-norm (one barrier; each thread finishes its own rows)
  #pragma unroll
  for (int rf = 0; rf < 4; ++rf) {
    #pragma unroll
    for (int e = 0; e < 4; ++e) {
      float p = acc2[rf][0][e] * acc2[rf][0][e] + acc2[rf][1][e] * acc2[rf][1][e];
      p += __shfl_xor(p, 1, 16); p += __shfl_xor(p, 2, 16);
      p += __shfl_xor(p, 4, 16); p += __shfl_xor(p, 8, 16);
      if (q == 0) s_red[(16 * rf + 4 * g + e) * 4 + wid] = p;
    }
  }
  __syncthreads();
  #pragma unroll
  for (int rf = 0; rf < 4; ++rf) {
    #pragma unroll
    for (int e = 0; e < 4; ++e) {
      int row = 16 * rf + 4 * g + e;
      int grow = i0 + row;
      if (grow < NITEMS) {
        float s = s_red[row * 4] + s_red[row * 4 + 1] + s_red[row * 4 + 2] + s_red[row * 4 + 3];
        float sc = 1.f / fmaxf(sqrtf(s), 1e-12f);
        #pragma unroll
        for (int cf = 0; cf < 2; ++cf)
          outp[(size_t)grow * TD + wid * 32 + cf * 16 + q] = acc2[rf][cf][e] * sc;
      }
    }
  }
}

// ======================= USER tower: direct-fragment, single-barrier =======================
__global__ __launch_bounds__(256, 3) void user_mlp(
    const float* __restrict__ gcn_user, const ushort* __restrict__ repB,
    const ushort* __restrict__ W1P, const float* __restrict__ b1,
    const ushort* __restrict__ W2P, const float* __restrict__ b2,
    float* __restrict__ outp)
{
  __shared__ __align__(16) ushort s_h[32 * 264];
  __shared__ float s_red[32 * 4];

  const int tid = threadIdx.x;
  const int wid = tid >> 6, lane = tid & 63, g = lane >> 4, q = lane & 15;
  const int i0 = blockIdx.x * 32;

  const ushort* bb1 = W1P + (wid * 64 + q) * 32 + g * 8;
  bf16x8 bcur[4];
  #pragma unroll
  for (int cf = 0; cf < 4; ++cf) bcur[cf] = ldfrag(bb1 + cf * 512);

  // ---- GEMM1: [32 x 256] @ [256 x 256]
  f32x4 acc[2][4];
  #pragma unroll
  for (int cf = 0; cf < 4; ++cf) {
    float bv = b1[wid * 64 + cf * 16 + q];
    f32x4 t = {bv, bv, bv, bv};
    acc[0][cf] = t; acc[1][cf] = t;
  }
  #pragma unroll
  for (int kb = 0; kb < 8; ++kb) {
    bf16x8 bnxt[4];
    if (kb < 7) {
      #pragma unroll
      for (int cf = 0; cf < 4; ++cf) bnxt[cf] = ldfrag(bb1 + (kb + 1) * 8192 + cf * 512);
    }
    bf16x8 af[2];
    if (kb < 4) {
      #pragma unroll
      for (int rf = 0; rf < 2; ++rf) {
        const float* rp = gcn_user + (size_t)(i0 + q + 16 * rf) * GCN + kb * 32 + g * 8;
        af[rf] = pack8c(*(const float4*)rp, *(const float4*)(rp + 4));
      }
    } else {
      #pragma unroll
      for (int rf = 0; rf < 2; ++rf)
        af[rf] = ldfrag(repB + (size_t)(i0 + q + 16 * rf) * TD + (kb - 4) * 32 + g * 8);
    }
    #pragma unroll
    for (int rf = 0; rf < 2; ++rf)
      #pragma unroll
      for (int cf = 0; cf < 4; ++cf)
        acc[rf][cf] = __builtin_amdgcn_mfma_f32_16x16x32_bf16(af[rf], bcur[cf], acc[rf][cf], 0, 0, 0);
    if (kb < 7) {
      #pragma unroll
      for (int cf = 0; cf < 4; ++cf) bcur[cf] = bnxt[cf];
    }
  }

  const ushort* bb2 = W2P + (wid * 32 + q) * 32 + g * 8;
  bf16x8 b2cur[2];
  #pragma unroll
  for (int cf = 0; cf < 2; ++cf) b2cur[cf] = ldfrag(bb2 + cf * 512);

  #pragma unroll
  for (int rf = 0; rf < 2; ++rf)
    #pragma unroll
    for (int cf = 0; cf < 4; ++cf)
      #pragma unroll
      for (int e = 0; e < 4; ++e)
        s_h[(16 * rf + 4 * g + e) * 264 + wid * 64 + cf * 16 + q] = bfb(fmaxf(acc[rf][cf][e], 0.f));
  __syncthreads();

  f32x4 acc2[2][2];
  #pragma unroll
  for (int cf = 0; cf < 2; ++cf) {
    float bv = b2[wid * 32 + cf * 16 + q];
    f32x4 t = {bv, bv, bv, bv};
    acc2[0][cf] = t; acc2[1][cf] = t;
  }
  #pragma unroll
  for (int kb = 0; kb < 8; ++kb) {
    bf16x8 bnxt[2];
    if (kb < 7) {
      #pragma unroll
      for (int cf = 0; cf < 2; ++cf) bnxt[cf] = ldfrag(bb2 + (kb + 1) * 4096 + cf * 512);
    }
    bf16x8 af[2];
    #pragma unroll
    for (int rf = 0; rf < 2; ++rf) af[rf] = ldfrag(&s_h[(16 * rf + q) * 264 + kb * 32 + g * 8]);
    #pragma unroll
    for (int rf = 0; rf < 2; ++rf)
      #pragma unroll
      for (int cf = 0; cf < 2; ++cf)
        acc2[rf][cf] = __builtin_amdgcn_mfma_f32_16x16x32_bf16(af[rf], b2cur[cf], acc2[rf][cf], 0, 0, 0);
    if (kb < 7) {
      #pragma unroll
      for (int cf = 0; cf < 2; ++cf) b2cur[cf] = bnxt[cf];
    }
  }

  #pragma unroll
  for (int rf = 0; rf < 2; ++rf) {
    #pragma unroll
    for (int e = 0; e < 4; ++e) {
      float p = acc2[rf][0][e] * acc2[rf][0][e] + acc2[rf][1][e] * acc2[rf][1][e];
      p += __shfl_xor(p, 1, 16); p += __shfl_xor(p, 2, 16);
      p += __shfl_xor(p, 4, 16); p += __shfl_xor(p, 8, 16);
      if (q == 0) s_red[(16 * rf + 4 * g + e) * 4 + wid] = p;
    }
  }
  __syncthreads();
  #pragma unroll
  for (int rf = 0; rf < 2; ++rf) {
    #pragma unroll
    for (int e = 0; e < 4; ++e) {
      int row = 16 * rf + 4 * g + e;
      float s = s_red[row * 4] + s_red[row * 4 + 1] + s_red[row * 4 + 2] + s_red[row * 4 + 3];
      float sc = 1.f / fmaxf(sqrtf(s), 1e-12f);
      #pragma unroll
      for (int cf = 0; cf < 2; ++cf)
        outp[(size_t)(i0 + row) * TD + wid * 32 + cf * 16 + q] = acc2[rf][cf][e] * sc;
    }
  }
}

// ======================= qt = gue @ WqkS + bqk =======================
__global__ __launch_bounds__(256) void qt_kernel(
    const float* __restrict__ gcn_user, const float* __restrict__ WqkS,
    const float* __restrict__ bqk, float* __restrict__ qt)
{
  __shared__ float s_gue[16 * 132];
  const int tid = threadIdx.x;
  const int u0 = blockIdx.x * 16;
  #pragma unroll
  for (int r = 0; r < 8; ++r) {
    int lin = r * 256 + tid;
    int u = lin >> 7, c = lin & 127;
    s_gue[u * 132 + c] = gcn_user[(size_t)(u0 + u) * GCN + c];
  }
  __syncthreads();
  const int ul = tid >> 4, tx = tid & 15, c0 = tx * 8;
  float a[8];
  { float4 b4 = *(const float4*)(bqk + c0); float4 b5 = *(const float4*)(bqk + c0 + 4);
    a[0]=b4.x; a[1]=b4.y; a[2]=b4.z; a[3]=b4.w; a[4]=b5.x; a[5]=b5.y; a[6]=b5.z; a[7]=b5.w; }
  for (int g = 0; g < 128; ++g) {
    float x = s_gue[ul * 132 + g];
    float4 w4 = *(const float4*)(WqkS + g * 128 + c0);
    float4 w5 = *(const float4*)(WqkS + g * 128 + c0 + 4);
    a[0] = fmaf(x, w4.x, a[0]); a[1] = fmaf(x, w4.y, a[1]);
    a[2] = fmaf(x, w4.z, a[2]); a[3] = fmaf(x, w4.w, a[3]);
    a[4] = fmaf(x, w5.x, a[4]); a[5] = fmaf(x, w5.y, a[5]);
    a[6] = fmaf(x, w5.z, a[6]); a[7] = fmaf(x, w5.w, a[7]);
  }
  float* op = qt + (size_t)(u0 + ul) * TD + c0;
  *(float4*)op = make_float4(a[0], a[1], a[2], a[3]);
  *(float4*)(op + 4) = make_float4(a[4], a[5], a[6], a[7]);
}

// ======================= attention: one wave per user, f32 gather from `out` =======================
__global__ __launch_bounds__(256) void attn_kernel(
    const int* __restrict__ user_items, const float* __restrict__ qt,
    const float* __restrict__ itemE, ushort* __restrict__ repB)
{
  __shared__ int s_idx[4][52];
  const int tid = threadIdx.x;
  const int wid = tid >> 6, lane = tid & 63, g = lane >> 4, q = lane & 15;
  const int u = blockIdx.x * 4 + wid;
  const int c0 = q * 8;

  if (lane < 52) s_idx[wid][lane] = (lane < 50) ? user_items[(size_t)u * RK + lane] : 0;
  float4 qv0, qv1;
  qv0 = *(const float4*)(qt + (size_t)u * TD + c0);
  qv1 = *(const float4*)(qt + (size_t)u * TD + c0 + 4);
  // s_idx is wave-local: no block barrier needed

  float4 h0[13], h1[13]; float sc[13];
  #pragma unroll
  for (int i = 0; i < 13; ++i) {
    int j = 4 * i + g;
    int idx = s_idx[wid][j];
    const float* hp = itemE + (size_t)idx * TD + c0;
    h0[i] = *(const float4*)hp;
    h1[i] = *(const float4*)(hp + 4);
    float p = h0[i].x * qv0.x + h0[i].y * qv0.y + h0[i].z * qv0.z + h0[i].w * qv0.w
            + h1[i].x * qv1.x + h1[i].y * qv1.y + h1[i].z * qv1.z + h1[i].w * qv1.w;
    p += __shfl_xor(p, 1, 16); p += __shfl_xor(p, 2, 16);
    p += __shfl_xor(p, 4, 16); p += __shfl_xor(p, 8, 16);
    sc[i] = (j < RK) ? p : -3.0e38f;
  }
  float m = sc[0];
  #pragma unroll
  for (int i = 1; i < 13; ++i) m = fmaxf(m, sc[i]);
  m = fmaxf(m, __shfl_xor(m, 16, 64));
  m = fmaxf(m, __shfl_xor(m, 32, 64));
  float ssum = 0.f;
  #pragma unroll
  for (int i = 0; i < 13; ++i) { sc[i] = __expf(sc[i] - m); ssum += sc[i]; }
  ssum += __shfl_xor(ssum, 16, 64);
  ssum += __shfl_xor(ssum, 32, 64);
  const float inv = 1.f / ssum;
  float rep[8] = {0, 0, 0, 0, 0, 0, 0, 0};
  #pragma unroll
  for (int i = 0; i < 13; ++i) {
    float a = sc[i] * inv;
    rep[0] = fmaf(a, h0[i].x, rep[0]); rep[1] = fmaf(a, h0[i].y, rep[1]);
    rep[2] = fmaf(a, h0[i].z, rep[2]); rep[3] = fmaf(a, h0[i].w, rep[3]);
    rep[4] = fmaf(a, h1[i].x, rep[4]); rep[5] = fmaf(a, h1[i].y, rep[5]);
    rep[6] = fmaf(a, h1[i].z, rep[6]); rep[7] = fmaf(a, h1[i].w, rep[7]);
  }
  #pragma unroll
  for (int c = 0; c < 8; ++c) {
    rep[c] += __shfl_xor(rep[c], 16, 64);
    rep[c] += __shfl_xor(rep[c], 32, 64);
  }
  if (g == 0) {
    uint4 o;
    o.x = packbf2(rep[0], rep[1]); o.y = packbf2(rep[2], rep[3]);
    o.z = packbf2(rep[4], rep[5]); o.w = packbf2(rep[6], rep[7]);
    *(uint4*)(repB + (size_t)u * TD + c0) = o;
  }
}

extern "C" void kernel_launch(void* const* d_in, const int* in_sizes, int n_in,
                              void* d_out, int out_size, void* d_ws, size_t ws_size,
                              hipStream_t stream) {
  const float* item_feat  = (const float*)d_in[0];
  const float* gcn_item   = (const float*)d_in[1];
  const float* gcn_user   = (const float*)d_in[2];
  const int*   user_items = (const int*)  d_in[3];
  const float* Wg  = (const float*)d_in[4];
  const float* bg  = (const float*)d_in[5];
  const float* Wi1 = (const float*)d_in[6];
  const float* bi1 = (const float*)d_in[7];
  const float* Wi2 = (const float*)d_in[8];
  const float* bi2 = (const float*)d_in[9];
  const float* Wq  = (const float*)d_in[10];
  const float* bq  = (const float*)d_in[11];
  const float* Wk  = (const float*)d_in[12];
  // d_in[13] = bk: softmax-invariant, dropped
  const float* Wu1 = (const float*)d_in[14];
  const float* bu1 = (const float*)d_in[15];
  const float* Wu2 = (const float*)d_in[16];
  const float* bu2 = (const float*)d_in[17];
  float* out = (float*)d_out;

  // workspace layout (bytes): ~38.6 MB total
  char* ws = (char*)d_ws;
  ushort* Wi1P   = (ushort*)(ws + 0);         // 5*256*32*2  =  81920
  ushort* Wi2P   = (ushort*)(ws + 81920);     // 8*128*32*2  =  65536
  ushort* Wu1P   = (ushort*)(ws + 147456);    // 8*256*32*2  = 131072
  ushort* Wu2P   = (ushort*)(ws + 278528);    // 8*128*32*2  =  65536
  float*  WqkS   = (float*) (ws + 344064);    // 128*128*4   =  65536
  float*  bqk    = (float*) (ws + 409600);    // 128*4       =    512
  float*  qtb    = (float*) (ws + 410112);    // 16384*128*4 = 8388608
  ushort* gitemB = (ushort*)(ws + 8798720);   // 100032*128*2 = 25608192
  ushort* repB   = (ushort*)(ws + 34406912);  // 16384*128*2  = 4194304

  prep_all<<<6989, 256, 0, stream>>>(Wi1, Wi2, Wu1, Wu2, Wq, Wk, bq, gcn_item,
                                     Wi1P, Wi2P, Wu1P, Wu2P, WqkS, bqk, gitemB);
  item_mlp<<<(NITEMS + 63) / 64, 256, 0, stream>>>(
      gitemB, item_feat, Wg, bg, Wi1P, bi1, Wi2P, bi2, out);
  qt_kernel<<<NUSERS / 16, 256, 0, stream>>>(gcn_user, WqkS, bqk, qtb);
  attn_kernel<<<NUSERS / 4, 256, 0, stream>>>(user_items, qtb, out, repB);
  user_mlp<<<NUSERS / 32, 256, 0, stream>>>(
      gcn_user, repB, Wu1P, bu1, Wu2P, bu2, out + (size_t)NITEMS * TD);
}

// Round 8
// 144.430 us; speedup vs baseline: 1.1989x; 1.1962x over previous
//
#include <hip/hip_runtime.h>
#include <hip/hip_bf16.h>
#include <math.h>

#define NITEMS 100000
#define NUSERS 16384
#define GCN 128
#define GEO 32
#define HIDD 256
#define TD 128
#define RK 50

typedef unsigned int uint;
typedef unsigned short ushort;
typedef __bf16 bf16x8 __attribute__((ext_vector_type(8)));
typedef float f32x4 __attribute__((ext_vector_type(4)));

__device__ __forceinline__ ushort bfb(float x) {
  union { __hip_bfloat16 b; ushort u; } t; t.b = __float2bfloat16(x); return t.u;
}
__device__ __forceinline__ uint packbf2(float a, float b) {
  return (uint)bfb(a) | ((uint)bfb(b) << 16);
}
__device__ __forceinline__ float bflo(uint d) { return __uint_as_float(d << 16); }
__device__ __forceinline__ float bfhi(uint d) { return __uint_as_float(d & 0xffff0000u); }

union U4B { uint4 u; bf16x8 b; };
__device__ __forceinline__ bf16x8 ldfrag(const ushort* p) { U4B t; t.u = *(const uint4*)p; return t.b; }
__device__ __forceinline__ bf16x8 pack8c(float4 a0, float4 a1) {
  bf16x8 r;
  r[0] = (__bf16)a0.x; r[1] = (__bf16)a0.y; r[2] = (__bf16)a0.z; r[3] = (__bf16)a0.w;
  r[4] = (__bf16)a1.x; r[5] = (__bf16)a1.y; r[6] = (__bf16)a1.z; r[7] = (__bf16)a1.w;
  return r;
}

// ============ prep: weight bf16 convert (chunk-major [K/32][N][32]) + Wqk fold
// ============ + gcn_item f32->bf16 FRAGMENT-MAJOR [rowblk16][kb4][q16][g4][8] ============
__global__ __launch_bounds__(256) void prep_all(
    const float* __restrict__ Wi1, const float* __restrict__ Wi2,
    const float* __restrict__ Wu1, const float* __restrict__ Wu2,
    const float* __restrict__ Wq, const float* __restrict__ Wk,
    const float* __restrict__ bq, const float* __restrict__ gcn_item,
    ushort* __restrict__ Wi1P, ushort* __restrict__ Wi2P,
    ushort* __restrict__ Wu1P, ushort* __restrict__ Wu2P,
    float* __restrict__ WqkS, float* __restrict__ bqk,
    ushort* __restrict__ gitemT)
{
  int id = blockIdx.x * 256 + threadIdx.x;
  if (id < 40960) {                       // Wi1 [160][256]
    int k = id >> 8, c = id & 255;
    Wi1P[(k >> 5) * 8192 + c * 32 + (k & 31)] = bfb(Wi1[id]);
  } else if (id < 73728) {                // Wi2 [256][128]
    int i = id - 40960; int k = i >> 7, c = i & 127;
    Wi2P[(k >> 5) * 4096 + c * 32 + (k & 31)] = bfb(Wi2[i]);
  } else if (id < 139264) {               // Wu1 [256][256]
    int i = id - 73728; int k = i >> 8, c = i & 255;
    Wu1P[(k >> 5) * 8192 + c * 32 + (k & 31)] = bfb(Wu1[i]);
  } else if (id < 172032) {               // Wu2 [256][128]
    int i = id - 139264; int k = i >> 7, c = i & 127;
    Wu2P[(k >> 5) * 4096 + c * 32 + (k & 31)] = bfb(Wu2[i]);
  } else if (id < 188416) {               // WqkS[g][s] = Wq[g,:].Wk[s,:]
    int i = id - 172032; int g = i >> 7, s = i & 127;
    float acc = 0.f;
    for (int t = 0; t < 128; t += 4) {
      float4 a = *(const float4*)(Wq + g * 128 + t);
      float4 b = *(const float4*)(Wk + s * 128 + t);
      acc += a.x * b.x + a.y * b.y + a.z * b.z + a.w * b.w;
    }
    WqkS[g * 128 + s] = acc;
  } else if (id < 188544) {               // bqk[s] = bq.Wk[s,:]
    int s = id - 188416;
    float acc = 0.f;
    for (int t = 0; t < 128; t += 4) {
      float4 a = *(const float4*)(bq + t);
      float4 b = *(const float4*)(Wk + s * 128 + t);
      acc += a.x * b.x + a.y * b.y + a.z * b.z + a.w * b.w;
    }
    bqk[s] = acc;
  } else if (id < 1788544) {              // gcn_item -> bf16 fragment-major
    int u = id - 188544;                  // 16B-unit index, row-linear
    int r = u >> 4, cu = u & 15;
    size_t base = (size_t)r * GCN + cu * 8;
    float4 v0 = *(const float4*)(gcn_item + base);
    float4 v1 = *(const float4*)(gcn_item + base + 4);
    uint4 o;
    o.x = packbf2(v0.x, v0.y); o.y = packbf2(v0.z, v0.w);
    o.z = packbf2(v1.x, v1.y); o.w = packbf2(v1.z, v1.w);
    int kb = cu >> 2, g = cu & 3;
    size_t ou = (((size_t)(r >> 4) * 4 + kb) * 16 + (r & 15)) * 4 + g;
    *(uint4*)(gitemT + ou * 8) = o;
  } else if (id < 1789056) {              // zero pad rows 100000..100031
    int t = id - 1788544;
    int r = 100000 + (t >> 4), cu = t & 15;
    int kb = cu >> 2, g = cu & 3;
    size_t ou = (((size_t)(r >> 4) * 4 + kb) * 16 + (r & 15)) * 4 + g;
    uint4 z; z.x = 0; z.y = 0; z.z = 0; z.w = 0;
    *(uint4*)(gitemT + ou * 8) = z;
  }
}

// ======================= ITEM tower: coalesced direct-fragment, single-barrier =======================
// 64 rows/block, 4 waves split N. A-fragments: one uint4/lane from fragment-major
// gitemT (a wave's fragment load = one contiguous 1KB block). Dual-write epilogue
// (f32 out + bf16 itemB for the attention gather).
__global__ __launch_bounds__(256, 3) void item_mlp(
    const ushort* __restrict__ gitemT, const float* __restrict__ feat,
    const float* __restrict__ Wg, const float* __restrict__ bg,
    const ushort* __restrict__ W1P, const float* __restrict__ b1,
    const ushort* __restrict__ W2P, const float* __restrict__ b2,
    float* __restrict__ outp, ushort* __restrict__ outb)
{
  __shared__ __align__(16) ushort s_h[64 * 264];
  __shared__ float s_red[64 * 4];

  const int tid = threadIdx.x;
  const int wid = tid >> 6, lane = tid & 63, g = lane >> 4, q = lane & 15;
  const int i0 = blockIdx.x * 64;

  // B chunk-0 prefetch
  const ushort* bb1 = W1P + (wid * 64 + q) * 32 + g * 8;
  bf16x8 bcur[4];
  #pragma unroll
  for (int cf = 0; cf < 4; ++cf) bcur[cf] = ldfrag(bb1 + cf * 512);

  // chunk 0 (geo) in-register
  bf16x8 acur[4];
  {
    const float4 w0a = *(const float4*)(Wg + g * 8),      w0b = *(const float4*)(Wg + g * 8 + 4);
    const float4 w1a = *(const float4*)(Wg + 32 + g * 8), w1b = *(const float4*)(Wg + 32 + g * 8 + 4);
    const float4 ba  = *(const float4*)(bg + g * 8),      bb = *(const float4*)(bg + g * 8 + 4);
    #pragma unroll
    for (int rf = 0; rf < 4; ++rf) {
      int row = i0 + q + 16 * rf;
      if (row > NITEMS - 1) row = NITEMS - 1;   // clamp (stores guarded)
      float2 f = *(const float2*)(feat + 2 * (size_t)row);
      float4 lo, hi;
      lo.x = fmaxf(fmaf(f.x, w0a.x, fmaf(f.y, w1a.x, ba.x)), 0.f);
      lo.y = fmaxf(fmaf(f.x, w0a.y, fmaf(f.y, w1a.y, ba.y)), 0.f);
      lo.z = fmaxf(fmaf(f.x, w0a.z, fmaf(f.y, w1a.z, ba.z)), 0.f);
      lo.w = fmaxf(fmaf(f.x, w0a.w, fmaf(f.y, w1a.w, ba.w)), 0.f);
      hi.x = fmaxf(fmaf(f.x, w0b.x, fmaf(f.y, w1b.x, bb.x)), 0.f);
      hi.y = fmaxf(fmaf(f.x, w0b.y, fmaf(f.y, w1b.y, bb.y)), 0.f);
      hi.z = fmaxf(fmaf(f.x, w0b.z, fmaf(f.y, w1b.z, bb.z)), 0.f);
      hi.w = fmaxf(fmaf(f.x, w0b.w, fmaf(f.y, w1b.w, bb.w)), 0.f);
      acur[rf] = pack8c(lo, hi);
    }
  }

  // ---- GEMM1: [64 x 160] @ [160 x 256], depth-1 A+B prefetch, barrier-free
  f32x4 acc[4][4];
  #pragma unroll
  for (int cf = 0; cf < 4; ++cf) {
    float bv = b1[wid * 64 + cf * 16 + q];
    f32x4 t = {bv, bv, bv, bv};
    #pragma unroll
    for (int rf = 0; rf < 4; ++rf) acc[rf][cf] = t;
  }
  #pragma unroll
  for (int kb = 0; kb < 5; ++kb) {
    bf16x8 anxt[4], bnxt[4];
    if (kb < 4) {
      #pragma unroll
      for (int rf = 0; rf < 4; ++rf) {
        // fragment-major: rowblk = i0/16 + rf; contiguous 1KB per (rowblk,kb)
        size_t ou = (((size_t)(blockIdx.x * 4 + rf) * 4 + kb) * 16 + q) * 4 + g;
        anxt[rf] = ldfrag(gitemT + ou * 8);
      }
      #pragma unroll
      for (int cf = 0; cf < 4; ++cf) bnxt[cf] = ldfrag(bb1 + (kb + 1) * 8192 + cf * 512);
    }
    #pragma unroll
    for (int rf = 0; rf < 4; ++rf)
      #pragma unroll
      for (int cf = 0; cf < 4; ++cf)
        acc[rf][cf] = __builtin_amdgcn_mfma_f32_16x16x32_bf16(acur[rf], bcur[cf], acc[rf][cf], 0, 0, 0);
    if (kb < 4) {
      #pragma unroll
      for (int rf = 0; rf < 4; ++rf) acur[rf] = anxt[rf];
      #pragma unroll
      for (int cf = 0; cf < 4; ++cf) bcur[cf] = bnxt[cf];
    }
  }

  // GEMM2 chunk-0 B prefetch (issues before the barrier)
  const ushort* bb2 = W2P + (wid * 32 + q) * 32 + g * 8;
  bf16x8 b2cur[2];
  #pragma unroll
  for (int cf = 0; cf < 2; ++cf) b2cur[cf] = ldfrag(bb2 + cf * 512);

  // ---- relu(hidden) -> LDS
  #pragma unroll
  for (int rf = 0; rf < 4; ++rf)
    #pragma unroll
    for (int cf = 0; cf < 4; ++cf)
      #pragma unroll
      for (int e = 0; e < 4; ++e)
        s_h[(16 * rf + 4 * g + e) * 264 + wid * 64 + cf * 16 + q] = bfb(fmaxf(acc[rf][cf][e], 0.f));
  __syncthreads();   // the ONLY pre-GEMM2 barrier

  // ---- GEMM2: [64 x 256] @ [256 x 128], depth-1 B prefetch
  f32x4 acc2[4][2];
  #pragma unroll
  for (int cf = 0; cf < 2; ++cf) {
    float bv = b2[wid * 32 + cf * 16 + q];
    f32x4 t = {bv, bv, bv, bv};
    #pragma unroll
    for (int rf = 0; rf < 4; ++rf) acc2[rf][cf] = t;
  }
  #pragma unroll
  for (int kb = 0; kb < 8; ++kb) {
    bf16x8 bnxt[2];
    if (kb < 7) {
      #pragma unroll
      for (int cf = 0; cf < 2; ++cf) bnxt[cf] = ldfrag(bb2 + (kb + 1) * 4096 + cf * 512);
    }
    bf16x8 af[4];
    #pragma unroll
    for (int rf = 0; rf < 4; ++rf) af[rf] = ldfrag(&s_h[(16 * rf + q) * 264 + kb * 32 + g * 8]);
    #pragma unroll
    for (int rf = 0; rf < 4; ++rf)
      #pragma unroll
      for (int cf = 0; cf < 2; ++cf)
        acc2[rf][cf] = __builtin_amdgcn_mfma_f32_16x16x32_bf16(af[rf], b2cur[cf], acc2[rf][cf], 0, 0, 0);
    if (kb < 7) {
      #pragma unroll
      for (int cf = 0; cf < 2; ++cf) b2cur[cf] = bnxt[cf];
    }
  }

  // ---- row L2-norm
  #pragma unroll
  for (int rf = 0; rf < 4; ++rf) {
    #pragma unroll
    for (int e = 0; e < 4; ++e) {
      float p = acc2[rf][0][e] * acc2[rf][0][e] + acc2[rf][1][e] * acc2[rf][1][e];
      p += __shfl_xor(p, 1, 16); p += __shfl_xor(p, 2, 16);
      p += __shfl_xor(p, 4, 16); p += __shfl_xor(p, 8, 16);
      if (q == 0) s_red[(16 * rf + 4 * g + e) * 4 + wid] = p;
    }
  }
  __syncthreads();
  #pragma unroll
  for (int rf = 0; rf < 4; ++rf) {
    #pragma unroll
    for (int e = 0; e < 4; ++e) {
      int row = 16 * rf + 4 * g + e;
      int grow = i0 + row;
      if (grow < NITEMS) {
        float s = s_red[row * 4] + s_red[row * 4 + 1] + s_red[row * 4 + 2] + s_red[row * 4 + 3];
        float sc = 1.f / fmaxf(sqrtf(s), 1e-12f);
        #pragma unroll
        for (int cf = 0; cf < 2; ++cf) {
          float v = acc2[rf][cf][e] * sc;
          outp[(size_t)grow * TD + wid * 32 + cf * 16 + q] = v;
          outb[(size_t)grow * TD + wid * 32 + cf * 16 + q] = bfb(v);
        }
      }
    }
  }
}

// ======================= USER tower: direct-fragment, single-barrier =======================
__global__ __launch_bounds__(256, 3) void user_mlp(
    const float* __restrict__ gcn_user, const ushort* __restrict__ repB,
    const ushort* __restrict__ W1P, const float* __restrict__ b1,
    const ushort* __restrict__ W2P, const float* __restrict__ b2,
    float* __restrict__ outp)
{
  __shared__ __align__(16) ushort s_h[32 * 264];
  __shared__ float s_red[32 * 4];

  const int tid = threadIdx.x;
  const int wid = tid >> 6, lane = tid & 63, g = lane >> 4, q = lane & 15;
  const int i0 = blockIdx.x * 32;

  const ushort* bb1 = W1P + (wid * 64 + q) * 32 + g * 8;
  bf16x8 bcur[4];
  #pragma unroll
  for (int cf = 0; cf < 4; ++cf) bcur[cf] = ldfrag(bb1 + cf * 512);

  // ---- GEMM1: [32 x 256] @ [256 x 256]
  f32x4 acc[2][4];
  #pragma unroll
  for (int cf = 0; cf < 4; ++cf) {
    float bv = b1[wid * 64 + cf * 16 + q];
    f32x4 t = {bv, bv, bv, bv};
    acc[0][cf] = t; acc[1][cf] = t;
  }
  #pragma unroll
  for (int kb = 0; kb < 8; ++kb) {
    bf16x8 bnxt[4];
    if (kb < 7) {
      #pragma unroll
      for (int cf = 0; cf < 4; ++cf) bnxt[cf] = ldfrag(bb1 + (kb + 1) * 8192 + cf * 512);
    }
    bf16x8 af[2];
    if (kb < 4) {
      #pragma unroll
      for (int rf = 0; rf < 2; ++rf) {
        const float* rp = gcn_user + (size_t)(i0 + q + 16 * rf) * GCN + kb * 32 + g * 8;
        af[rf] = pack8c(*(const float4*)rp, *(const float4*)(rp + 4));
      }
    } else {
      #pragma unroll
      for (int rf = 0; rf < 2; ++rf)
        af[rf] = ldfrag(repB + (size_t)(i0 + q + 16 * rf) * TD + (kb - 4) * 32 + g * 8);
    }
    #pragma unroll
    for (int rf = 0; rf < 2; ++rf)
      #pragma unroll
      for (int cf = 0; cf < 4; ++cf)
        acc[rf][cf] = __builtin_amdgcn_mfma_f32_16x16x32_bf16(af[rf], bcur[cf], acc[rf][cf], 0, 0, 0);
    if (kb < 7) {
      #pragma unroll
      for (int cf = 0; cf < 4; ++cf) bcur[cf] = bnxt[cf];
    }
  }

  const ushort* bb2 = W2P + (wid * 32 + q) * 32 + g * 8;
  bf16x8 b2cur[2];
  #pragma unroll
  for (int cf = 0; cf < 2; ++cf) b2cur[cf] = ldfrag(bb2 + cf * 512);

  #pragma unroll
  for (int rf = 0; rf < 2; ++rf)
    #pragma unroll
    for (int cf = 0; cf < 4; ++cf)
      #pragma unroll
      for (int e = 0; e < 4; ++e)
        s_h[(16 * rf + 4 * g + e) * 264 + wid * 64 + cf * 16 + q] = bfb(fmaxf(acc[rf][cf][e], 0.f));
  __syncthreads();

  f32x4 acc2[2][2];
  #pragma unroll
  for (int cf = 0; cf < 2; ++cf) {
    float bv = b2[wid * 32 + cf * 16 + q];
    f32x4 t = {bv, bv, bv, bv};
    acc2[0][cf] = t; acc2[1][cf] = t;
  }
  #pragma unroll
  for (int kb = 0; kb < 8; ++kb) {
    bf16x8 bnxt[2];
    if (kb < 7) {
      #pragma unroll
      for (int cf = 0; cf < 2; ++cf) bnxt[cf] = ldfrag(bb2 + (kb + 1) * 4096 + cf * 512);
    }
    bf16x8 af[2];
    #pragma unroll
    for (int rf = 0; rf < 2; ++rf) af[rf] = ldfrag(&s_h[(16 * rf + q) * 264 + kb * 32 + g * 8]);
    #pragma unroll
    for (int rf = 0; rf < 2; ++rf)
      #pragma unroll
      for (int cf = 0; cf < 2; ++cf)
        acc2[rf][cf] = __builtin_amdgcn_mfma_f32_16x16x32_bf16(af[rf], b2cur[cf], acc2[rf][cf], 0, 0, 0);
    if (kb < 7) {
      #pragma unroll
      for (int cf = 0; cf < 2; ++cf) b2cur[cf] = bnxt[cf];
    }
  }

  #pragma unroll
  for (int rf = 0; rf < 2; ++rf) {
    #pragma unroll
    for (int e = 0; e < 4; ++e) {
      float p = acc2[rf][0][e] * acc2[rf][0][e] + acc2[rf][1][e] * acc2[rf][1][e];
      p += __shfl_xor(p, 1, 16); p += __shfl_xor(p, 2, 16);
      p += __shfl_xor(p, 4, 16); p += __shfl_xor(p, 8, 16);
      if (q == 0) s_red[(16 * rf + 4 * g + e) * 4 + wid] = p;
    }
  }
  __syncthreads();
  #pragma unroll
  for (int rf = 0; rf < 2; ++rf) {
    #pragma unroll
    for (int e = 0; e < 4; ++e) {
      int row = 16 * rf + 4 * g + e;
      float s = s_red[row * 4] + s_red[row * 4 + 1] + s_red[row * 4 + 2] + s_red[row * 4 + 3];
      float sc = 1.f / fmaxf(sqrtf(s), 1e-12f);
      #pragma unroll
      for (int cf = 0; cf < 2; ++cf)
        outp[(size_t)(i0 + row) * TD + wid * 32 + cf * 16 + q] = acc2[rf][cf][e] * sc;
    }
  }
}

// ======================= qt = gue @ WqkS + bqk =======================
__global__ __launch_bounds__(256) void qt_kernel(
    const float* __restrict__ gcn_user, const float* __restrict__ WqkS,
    const float* __restrict__ bqk, float* __restrict__ qt)
{
  __shared__ float s_gue[16 * 132];
  const int tid = threadIdx.x;
  const int u0 = blockIdx.x * 16;
  #pragma unroll
  for (int r = 0; r < 8; ++r) {
    int lin = r * 256 + tid;
    int u = lin >> 7, c = lin & 127;
    s_gue[u * 132 + c] = gcn_user[(size_t)(u0 + u) * GCN + c];
  }
  __syncthreads();
  const int ul = tid >> 4, tx = tid & 15, c0 = tx * 8;
  float a[8];
  { float4 b4 = *(const float4*)(bqk + c0); float4 b5 = *(const float4*)(bqk + c0 + 4);
    a[0]=b4.x; a[1]=b4.y; a[2]=b4.z; a[3]=b4.w; a[4]=b5.x; a[5]=b5.y; a[6]=b5.z; a[7]=b5.w; }
  for (int g = 0; g < 128; ++g) {
    float x = s_gue[ul * 132 + g];
    float4 w4 = *(const float4*)(WqkS + g * 128 + c0);
    float4 w5 = *(const float4*)(WqkS + g * 128 + c0 + 4);
    a[0] = fmaf(x, w4.x, a[0]); a[1] = fmaf(x, w4.y, a[1]);
    a[2] = fmaf(x, w4.z, a[2]); a[3] = fmaf(x, w4.w, a[3]);
    a[4] = fmaf(x, w5.x, a[4]); a[5] = fmaf(x, w5.y, a[5]);
    a[6] = fmaf(x, w5.z, a[6]); a[7] = fmaf(x, w5.w, a[7]);
  }
  float* op = qt + (size_t)(u0 + ul) * TD + c0;
  *(float4*)op = make_float4(a[0], a[1], a[2], a[3]);
  *(float4*)(op + 4) = make_float4(a[4], a[5], a[6], a[7]);
}

// ======================= attention: one wave per user, bf16 gather =======================
__global__ __launch_bounds__(256) void attn_kernel(
    const int* __restrict__ user_items, const float* __restrict__ qt,
    const ushort* __restrict__ itemB, ushort* __restrict__ repB)
{
  __shared__ int s_idx[4][52];
  const int tid = threadIdx.x;
  const int wid = tid >> 6, lane = tid & 63, g = lane >> 4, q = lane & 15;
  const int u = blockIdx.x * 4 + wid;
  const int c0 = q * 8;

  if (lane < 52) s_idx[wid][lane] = (lane < 50) ? user_items[(size_t)u * RK + lane] : 0;
  float qv[8];
  { float4 a = *(const float4*)(qt + (size_t)u * TD + c0);
    float4 b = *(const float4*)(qt + (size_t)u * TD + c0 + 4);
    qv[0]=a.x; qv[1]=a.y; qv[2]=a.z; qv[3]=a.w; qv[4]=b.x; qv[5]=b.y; qv[6]=b.z; qv[7]=b.w; }
  // s_idx is wave-local: no block barrier needed

  uint4 h[13]; float sc[13];
  #pragma unroll
  for (int i = 0; i < 13; ++i) {
    int j = 4 * i + g;
    int idx = s_idx[wid][j];
    h[i] = *(const uint4*)(itemB + (size_t)idx * TD + c0);
    float p = bflo(h[i].x) * qv[0] + bfhi(h[i].x) * qv[1]
            + bflo(h[i].y) * qv[2] + bfhi(h[i].y) * qv[3]
            + bflo(h[i].z) * qv[4] + bfhi(h[i].z) * qv[5]
            + bflo(h[i].w) * qv[6] + bfhi(h[i].w) * qv[7];
    p += __shfl_xor(p, 1, 16); p += __shfl_xor(p, 2, 16);
    p += __shfl_xor(p, 4, 16); p += __shfl_xor(p, 8, 16);
    sc[i] = (j < RK) ? p : -3.0e38f;
  }
  float m = sc[0];
  #pragma unroll
  for (int i = 1; i < 13; ++i) m = fmaxf(m, sc[i]);
  m = fmaxf(m, __shfl_xor(m, 16, 64));
  m = fmaxf(m, __shfl_xor(m, 32, 64));
  float ssum = 0.f;
  #pragma unroll
  for (int i = 0; i < 13; ++i) { sc[i] = __expf(sc[i] - m); ssum += sc[i]; }
  ssum += __shfl_xor(ssum, 16, 64);
  ssum += __shfl_xor(ssum, 32, 64);
  const float inv = 1.f / ssum;
  float rep[8] = {0, 0, 0, 0, 0, 0, 0, 0};
  #pragma unroll
  for (int i = 0; i < 13; ++i) {
    float a = sc[i] * inv;
    rep[0] = fmaf(a, bflo(h[i].x), rep[0]); rep[1] = fmaf(a, bfhi(h[i].x), rep[1]);
    rep[2] = fmaf(a, bflo(h[i].y), rep[2]); rep[3] = fmaf(a, bfhi(h[i].y), rep[3]);
    rep[4] = fmaf(a, bflo(h[i].z), rep[4]); rep[5] = fmaf(a, bfhi(h[i].z), rep[5]);
    rep[6] = fmaf(a, bflo(h[i].w), rep[6]); rep[7] = fmaf(a, bfhi(h[i].w), rep[7]);
  }
  #pragma unroll
  for (int c = 0; c < 8; ++c) {
    rep[c] += __shfl_xor(rep[c], 16, 64);
    rep[c] += __shfl_xor(rep[c], 32, 64);
  }
  if (g == 0) {
    uint4 o;
    o.x = packbf2(rep[0], rep[1]); o.y = packbf2(rep[2], rep[3]);
    o.z = packbf2(rep[4], rep[5]); o.w = packbf2(rep[6], rep[7]);
    *(uint4*)(repB + (size_t)u * TD + c0) = o;
  }
}

extern "C" void kernel_launch(void* const* d_in, const int* in_sizes, int n_in,
                              void* d_out, int out_size, void* d_ws, size_t ws_size,
                              hipStream_t stream) {
  const float* item_feat  = (const float*)d_in[0];
  const float* gcn_item   = (const float*)d_in[1];
  const float* gcn_user   = (const float*)d_in[2];
  const int*   user_items = (const int*)  d_in[3];
  const float* Wg  = (const float*)d_in[4];
  const float* bg  = (const float*)d_in[5];
  const float* Wi1 = (const float*)d_in[6];
  const float* bi1 = (const float*)d_in[7];
  const float* Wi2 = (const float*)d_in[8];
  const float* bi2 = (const float*)d_in[9];
  const float* Wq  = (const float*)d_in[10];
  const float* bq  = (const float*)d_in[11];
  const float* Wk  = (const float*)d_in[12];
  // d_in[13] = bk: softmax-invariant, dropped
  const float* Wu1 = (const float*)d_in[14];
  const float* bu1 = (const float*)d_in[15];
  const float* Wu2 = (const float*)d_in[16];
  const float* bu2 = (const float*)d_in[17];
  float* out = (float*)d_out;

  // workspace layout (bytes): ~64.2 MB total
  char* ws = (char*)d_ws;
  ushort* Wi1P   = (ushort*)(ws + 0);         // 5*256*32*2  =  81920
  ushort* Wi2P   = (ushort*)(ws + 81920);     // 8*128*32*2  =  65536
  ushort* Wu1P   = (ushort*)(ws + 147456);    // 8*256*32*2  = 131072
  ushort* Wu2P   = (ushort*)(ws + 278528);    // 8*128*32*2  =  65536
  float*  WqkS   = (float*) (ws + 344064);    // 128*128*4   =  65536
  float*  bqk    = (float*) (ws + 409600);    // 128*4       =    512
  float*  qtb    = (float*) (ws + 410112);    // 16384*128*4 = 8388608
  ushort* gitemT = (ushort*)(ws + 8798720);   // 100032*128*2 = 25608192
  ushort* itemB  = (ushort*)(ws + 34406912);  // 100000*128*2 = 25600000
  ushort* repB   = (ushort*)(ws + 60006912);  // 16384*128*2  = 4194304

  prep_all<<<6989, 256, 0, stream>>>(Wi1, Wi2, Wu1, Wu2, Wq, Wk, bq, gcn_item,
                                     Wi1P, Wi2P, Wu1P, Wu2P, WqkS, bqk, gitemT);
  item_mlp<<<(NITEMS + 63) / 64, 256, 0, stream>>>(
      gitemT, item_feat, Wg, bg, Wi1P, bi1, Wi2P, bi2, out, itemB);
  qt_kernel<<<NUSERS / 16, 256, 0, stream>>>(gcn_user, WqkS, bqk, qtb);
  attn_kernel<<<NUSERS / 4, 256, 0, stream>>>(user_items, qtb, itemB, repB);
  user_mlp<<<NUSERS / 32, 256, 0, stream>>>(
      gcn_user, repB, Wu1P, bu1, Wu2P, bu2, out + (size_t)NITEMS * TD);
}

// Round 9
// 140.709 us; speedup vs baseline: 1.2306x; 1.0264x over previous
//
#include <hip/hip_runtime.h>
#include <hip/hip_bf16.h>
#include <math.h>

#define NITEMS 100000
#define NUSERS 16384
#define GCN 128
#define GEO 32
#define HIDD 256
#define TD 128
#define RK 50

typedef unsigned int uint;
typedef unsigned short ushort;
typedef __bf16 bf16x8 __attribute__((ext_vector_type(8)));
typedef float f32x4 __attribute__((ext_vector_type(4)));

__device__ __forceinline__ ushort bfb(float x) {
  union { __hip_bfloat16 b; ushort u; } t; t.b = __float2bfloat16(x); return t.u;
}
__device__ __forceinline__ uint packbf2(float a, float b) {
  return (uint)bfb(a) | ((uint)bfb(b) << 16);
}
__device__ __forceinline__ float bflo(uint d) { return __uint_as_float(d << 16); }
__device__ __forceinline__ float bfhi(uint d) { return __uint_as_float(d & 0xffff0000u); }

union U4B { uint4 u; bf16x8 b; };
__device__ __forceinline__ bf16x8 ldfrag(const ushort* p) { U4B t; t.u = *(const uint4*)p; return t.b; }
__device__ __forceinline__ bf16x8 pack8c(float4 a0, float4 a1) {
  bf16x8 r;
  r[0] = (__bf16)a0.x; r[1] = (__bf16)a0.y; r[2] = (__bf16)a0.z; r[3] = (__bf16)a0.w;
  r[4] = (__bf16)a1.x; r[5] = (__bf16)a1.y; r[6] = (__bf16)a1.z; r[7] = (__bf16)a1.w;
  return r;
}

// ============ prep: weight bf16 convert (chunk-major [K/32][N][32]) + Wqk fold
// ============ + gcn_item f32->bf16 FRAGMENT-MAJOR [rowblk16][kb4][q16][g4][8] ============
__global__ __launch_bounds__(256) void prep_all(
    const float* __restrict__ Wi1, const float* __restrict__ Wi2,
    const float* __restrict__ Wu1, const float* __restrict__ Wu2,
    const float* __restrict__ Wq, const float* __restrict__ Wk,
    const float* __restrict__ bq, const float* __restrict__ gcn_item,
    ushort* __restrict__ Wi1P, ushort* __restrict__ Wi2P,
    ushort* __restrict__ Wu1P, ushort* __restrict__ Wu2P,
    float* __restrict__ WqkS, float* __restrict__ bqk,
    ushort* __restrict__ gitemT)
{
  int id = blockIdx.x * 256 + threadIdx.x;
  if (id < 40960) {                       // Wi1 [160][256]
    int k = id >> 8, c = id & 255;
    Wi1P[(k >> 5) * 8192 + c * 32 + (k & 31)] = bfb(Wi1[id]);
  } else if (id < 73728) {                // Wi2 [256][128]
    int i = id - 40960; int k = i >> 7, c = i & 127;
    Wi2P[(k >> 5) * 4096 + c * 32 + (k & 31)] = bfb(Wi2[i]);
  } else if (id < 139264) {               // Wu1 [256][256]
    int i = id - 73728; int k = i >> 8, c = i & 255;
    Wu1P[(k >> 5) * 8192 + c * 32 + (k & 31)] = bfb(Wu1[i]);
  } else if (id < 172032) {               // Wu2 [256][128]
    int i = id - 139264; int k = i >> 7, c = i & 127;
    Wu2P[(k >> 5) * 4096 + c * 32 + (k & 31)] = bfb(Wu2[i]);
  } else if (id < 188416) {               // WqkS[g][s] = Wq[g,:].Wk[s,:]
    int i = id - 172032; int g = i >> 7, s = i & 127;
    float acc = 0.f;
    for (int t = 0; t < 128; t += 4) {
      float4 a = *(const float4*)(Wq + g * 128 + t);
      float4 b = *(const float4*)(Wk + s * 128 + t);
      acc += a.x * b.x + a.y * b.y + a.z * b.z + a.w * b.w;
    }
    WqkS[g * 128 + s] = acc;
  } else if (id < 188544) {               // bqk[s] = bq.Wk[s,:]
    int s = id - 188416;
    float acc = 0.f;
    for (int t = 0; t < 128; t += 4) {
      float4 a = *(const float4*)(bq + t);
      float4 b = *(const float4*)(Wk + s * 128 + t);
      acc += a.x * b.x + a.y * b.y + a.z * b.z + a.w * b.w;
    }
    bqk[s] = acc;
  } else if (id < 1788544) {              // gcn_item -> bf16 fragment-major
    int u = id - 188544;                  // 16B-unit index, row-linear
    int r = u >> 4, cu = u & 15;
    size_t base = (size_t)r * GCN + cu * 8;
    float4 v0 = *(const float4*)(gcn_item + base);
    float4 v1 = *(const float4*)(gcn_item + base + 4);
    uint4 o;
    o.x = packbf2(v0.x, v0.y); o.y = packbf2(v0.z, v0.w);
    o.z = packbf2(v1.x, v1.y); o.w = packbf2(v1.z, v1.w);
    int kb = cu >> 2, g = cu & 3;
    size_t ou = (((size_t)(r >> 4) * 4 + kb) * 16 + (r & 15)) * 4 + g;
    *(uint4*)(gitemT + ou * 8) = o;
  } else if (id < 1789056) {              // zero pad rows 100000..100031
    int t = id - 1788544;
    int r = 100000 + (t >> 4), cu = t & 15;
    int kb = cu >> 2, g = cu & 3;
    size_t ou = (((size_t)(r >> 4) * 4 + kb) * 16 + (r & 15)) * 4 + g;
    uint4 z; z.x = 0; z.y = 0; z.z = 0; z.w = 0;
    *(uint4*)(gitemT + ou * 8) = z;
  }
}

// ======================= ITEM tower: ALL operands issued upfront, wait once =======================
// 64 rows/block, 4 waves split N. A (16 frags) + B1 (20 frags) issued back-to-back
// at entry -> one latency exposure instead of 13. Pure-MFMA K loops.
__global__ __launch_bounds__(256, 2) void item_mlp(
    const ushort* __restrict__ gitemT, const float* __restrict__ feat,
    const float* __restrict__ Wg, const float* __restrict__ bg,
    const ushort* __restrict__ W1P, const float* __restrict__ b1,
    const ushort* __restrict__ W2P, const float* __restrict__ b2,
    float* __restrict__ outp, ushort* __restrict__ outb)
{
  __shared__ __align__(16) ushort s_h[64 * 264];
  __shared__ float s_red[64 * 4];

  const int tid = threadIdx.x;
  const int wid = tid >> 6, lane = tid & 63, g = lane >> 4, q = lane & 15;
  const int i0 = blockIdx.x * 64;

  // ---- issue ALL GEMM1 operand loads now (one latency wall)
  bf16x8 afr[4][4];   // A chunks 1..4 (gcn part), fragment-major: contiguous 1KB/wave
  #pragma unroll
  for (int kb = 0; kb < 4; ++kb)
    #pragma unroll
    for (int rf = 0; rf < 4; ++rf)
      afr[kb][rf] = ldfrag(gitemT + ((((size_t)(blockIdx.x * 4 + rf) * 4 + kb) * 16 + q) * 4 + g) * 8);

  const ushort* bb1 = W1P + (wid * 64 + q) * 32 + g * 8;
  bf16x8 bfr[5][4];
  #pragma unroll
  for (int kb = 0; kb < 5; ++kb)
    #pragma unroll
    for (int cf = 0; cf < 4; ++cf)
      bfr[kb][cf] = ldfrag(bb1 + kb * 8192 + cf * 512);

  // ---- geo chunk computed in-register (overlaps the loads above)
  bf16x8 ageo[4];
  {
    const float4 w0a = *(const float4*)(Wg + g * 8),      w0b = *(const float4*)(Wg + g * 8 + 4);
    const float4 w1a = *(const float4*)(Wg + 32 + g * 8), w1b = *(const float4*)(Wg + 32 + g * 8 + 4);
    const float4 ba  = *(const float4*)(bg + g * 8),      bb = *(const float4*)(bg + g * 8 + 4);
    #pragma unroll
    for (int rf = 0; rf < 4; ++rf) {
      int row = i0 + q + 16 * rf;
      if (row > NITEMS - 1) row = NITEMS - 1;   // clamp (stores guarded)
      float2 f = *(const float2*)(feat + 2 * (size_t)row);
      float4 lo, hi;
      lo.x = fmaxf(fmaf(f.x, w0a.x, fmaf(f.y, w1a.x, ba.x)), 0.f);
      lo.y = fmaxf(fmaf(f.x, w0a.y, fmaf(f.y, w1a.y, ba.y)), 0.f);
      lo.z = fmaxf(fmaf(f.x, w0a.z, fmaf(f.y, w1a.z, ba.z)), 0.f);
      lo.w = fmaxf(fmaf(f.x, w0a.w, fmaf(f.y, w1a.w, ba.w)), 0.f);
      hi.x = fmaxf(fmaf(f.x, w0b.x, fmaf(f.y, w1b.x, bb.x)), 0.f);
      hi.y = fmaxf(fmaf(f.x, w0b.y, fmaf(f.y, w1b.y, bb.y)), 0.f);
      hi.z = fmaxf(fmaf(f.x, w0b.z, fmaf(f.y, w1b.z, bb.z)), 0.f);
      hi.w = fmaxf(fmaf(f.x, w0b.w, fmaf(f.y, w1b.w, bb.w)), 0.f);
      ageo[rf] = pack8c(lo, hi);
    }
  }

  // ---- GEMM1: pure MFMA (all operands in registers)
  f32x4 acc[4][4];
  #pragma unroll
  for (int cf = 0; cf < 4; ++cf) {
    float bv = b1[wid * 64 + cf * 16 + q];
    f32x4 t = {bv, bv, bv, bv};
    #pragma unroll
    for (int rf = 0; rf < 4; ++rf) acc[rf][cf] = t;
  }
  #pragma unroll
  for (int rf = 0; rf < 4; ++rf)
    #pragma unroll
    for (int cf = 0; cf < 4; ++cf)
      acc[rf][cf] = __builtin_amdgcn_mfma_f32_16x16x32_bf16(ageo[rf], bfr[0][cf], acc[rf][cf], 0, 0, 0);
  #pragma unroll
  for (int kb = 0; kb < 4; ++kb)
    #pragma unroll
    for (int rf = 0; rf < 4; ++rf)
      #pragma unroll
      for (int cf = 0; cf < 4; ++cf)
        acc[rf][cf] = __builtin_amdgcn_mfma_f32_16x16x32_bf16(afr[kb][rf], bfr[kb + 1][cf], acc[rf][cf], 0, 0, 0);

  // ---- issue ALL GEMM2 B loads (latency hides under hidden store + barrier)
  const ushort* bb2 = W2P + (wid * 32 + q) * 32 + g * 8;
  bf16x8 b2f[8][2];
  #pragma unroll
  for (int kb = 0; kb < 8; ++kb)
    #pragma unroll
    for (int cf = 0; cf < 2; ++cf)
      b2f[kb][cf] = ldfrag(bb2 + kb * 4096 + cf * 512);

  // ---- relu(hidden) -> LDS
  #pragma unroll
  for (int rf = 0; rf < 4; ++rf)
    #pragma unroll
    for (int cf = 0; cf < 4; ++cf)
      #pragma unroll
      for (int e = 0; e < 4; ++e)
        s_h[(16 * rf + 4 * g + e) * 264 + wid * 64 + cf * 16 + q] = bfb(fmaxf(acc[rf][cf][e], 0.f));
  __syncthreads();   // the ONLY pre-GEMM2 barrier

  // ---- GEMM2: B in registers, A from LDS
  f32x4 acc2[4][2];
  #pragma unroll
  for (int cf = 0; cf < 2; ++cf) {
    float bv = b2[wid * 32 + cf * 16 + q];
    f32x4 t = {bv, bv, bv, bv};
    #pragma unroll
    for (int rf = 0; rf < 4; ++rf) acc2[rf][cf] = t;
  }
  #pragma unroll
  for (int kb = 0; kb < 8; ++kb) {
    bf16x8 af[4];
    #pragma unroll
    for (int rf = 0; rf < 4; ++rf) af[rf] = ldfrag(&s_h[(16 * rf + q) * 264 + kb * 32 + g * 8]);
    #pragma unroll
    for (int rf = 0; rf < 4; ++rf)
      #pragma unroll
      for (int cf = 0; cf < 2; ++cf)
        acc2[rf][cf] = __builtin_amdgcn_mfma_f32_16x16x32_bf16(af[rf], b2f[kb][cf], acc2[rf][cf], 0, 0, 0);
  }

  // ---- row L2-norm
  #pragma unroll
  for (int rf = 0; rf < 4; ++rf) {
    #pragma unroll
    for (int e = 0; e < 4; ++e) {
      float p = acc2[rf][0][e] * acc2[rf][0][e] + acc2[rf][1][e] * acc2[rf][1][e];
      p += __shfl_xor(p, 1, 16); p += __shfl_xor(p, 2, 16);
      p += __shfl_xor(p, 4, 16); p += __shfl_xor(p, 8, 16);
      if (q == 0) s_red[(16 * rf + 4 * g + e) * 4 + wid] = p;
    }
  }
  __syncthreads();
  #pragma unroll
  for (int rf = 0; rf < 4; ++rf) {
    #pragma unroll
    for (int e = 0; e < 4; ++e) {
      int row = 16 * rf + 4 * g + e;
      int grow = i0 + row;
      if (grow < NITEMS) {
        float s = s_red[row * 4] + s_red[row * 4 + 1] + s_red[row * 4 + 2] + s_red[row * 4 + 3];
        float sc = 1.f / fmaxf(sqrtf(s), 1e-12f);
        #pragma unroll
        for (int cf = 0; cf < 2; ++cf) {
          float v = acc2[rf][cf][e] * sc;
          outp[(size_t)grow * TD + wid * 32 + cf * 16 + q] = v;
          outb[(size_t)grow * TD + wid * 32 + cf * 16 + q] = bfb(v);
        }
      }
    }
  }
}

// ======================= USER tower: A upfront, B depth-1 =======================
__global__ __launch_bounds__(256, 3) void user_mlp(
    const float* __restrict__ gcn_user, const ushort* __restrict__ repB,
    const ushort* __restrict__ W1P, const float* __restrict__ b1,
    const ushort* __restrict__ W2P, const float* __restrict__ b2,
    float* __restrict__ outp)
{
  __shared__ __align__(16) ushort s_h[32 * 264];
  __shared__ float s_red[32 * 4];

  const int tid = threadIdx.x;
  const int wid = tid >> 6, lane = tid & 63, g = lane >> 4, q = lane & 15;
  const int i0 = blockIdx.x * 32;

  // ---- ALL A-fragments upfront (16 frags)
  bf16x8 auf[8][2];
  #pragma unroll
  for (int kb = 0; kb < 4; ++kb)
    #pragma unroll
    for (int rf = 0; rf < 2; ++rf) {
      const float* rp = gcn_user + (size_t)(i0 + q + 16 * rf) * GCN + kb * 32 + g * 8;
      auf[kb][rf] = pack8c(*(const float4*)rp, *(const float4*)(rp + 4));
    }
  #pragma unroll
  for (int kb = 4; kb < 8; ++kb)
    #pragma unroll
    for (int rf = 0; rf < 2; ++rf)
      auf[kb][rf] = ldfrag(repB + (size_t)(i0 + q + 16 * rf) * TD + (kb - 4) * 32 + g * 8);

  const ushort* bb1 = W1P + (wid * 64 + q) * 32 + g * 8;
  bf16x8 bcur[4];
  #pragma unroll
  for (int cf = 0; cf < 4; ++cf) bcur[cf] = ldfrag(bb1 + cf * 512);

  // ---- GEMM1: [32 x 256] @ [256 x 256]
  f32x4 acc[2][4];
  #pragma unroll
  for (int cf = 0; cf < 4; ++cf) {
    float bv = b1[wid * 64 + cf * 16 + q];
    f32x4 t = {bv, bv, bv, bv};
    acc[0][cf] = t; acc[1][cf] = t;
  }
  #pragma unroll
  for (int kb = 0; kb < 8; ++kb) {
    bf16x8 bnxt[4];
    if (kb < 7) {
      #pragma unroll
      for (int cf = 0; cf < 4; ++cf) bnxt[cf] = ldfrag(bb1 + (kb + 1) * 8192 + cf * 512);
    }
    #pragma unroll
    for (int rf = 0; rf < 2; ++rf)
      #pragma unroll
      for (int cf = 0; cf < 4; ++cf)
        acc[rf][cf] = __builtin_amdgcn_mfma_f32_16x16x32_bf16(auf[kb][rf], bcur[cf], acc[rf][cf], 0, 0, 0);
    if (kb < 7) {
      #pragma unroll
      for (int cf = 0; cf < 4; ++cf) bcur[cf] = bnxt[cf];
    }
  }

  const ushort* bb2 = W2P + (wid * 32 + q) * 32 + g * 8;
  bf16x8 b2f[8][2];
  #pragma unroll
  for (int kb = 0; kb < 8; ++kb)
    #pragma unroll
    for (int cf = 0; cf < 2; ++cf)
      b2f[kb][cf] = ldfrag(bb2 + kb * 4096 + cf * 512);

  #pragma unroll
  for (int rf = 0; rf < 2; ++rf)
    #pragma unroll
    for (int cf = 0; cf < 4; ++cf)
      #pragma unroll
      for (int e = 0; e < 4; ++e)
        s_h[(16 * rf + 4 * g + e) * 264 + wid * 64 + cf * 16 + q] = bfb(fmaxf(acc[rf][cf][e], 0.f));
  __syncthreads();

  f32x4 acc2[2][2];
  #pragma unroll
  for (int cf = 0; cf < 2; ++cf) {
    float bv = b2[wid * 32 + cf * 16 + q];
    f32x4 t = {bv, bv, bv, bv};
    acc2[0][cf] = t; acc2[1][cf] = t;
  }
  #pragma unroll
  for (int kb = 0; kb < 8; ++kb) {
    bf16x8 af[2];
    #pragma unroll
    for (int rf = 0; rf < 2; ++rf) af[rf] = ldfrag(&s_h[(16 * rf + q) * 264 + kb * 32 + g * 8]);
    #pragma unroll
    for (int rf = 0; rf < 2; ++rf)
      #pragma unroll
      for (int cf = 0; cf < 2; ++cf)
        acc2[rf][cf] = __builtin_amdgcn_mfma_f32_16x16x32_bf16(af[rf], b2f[kb][cf], acc2[rf][cf], 0, 0, 0);
  }

  #pragma unroll
  for (int rf = 0; rf < 2; ++rf) {
    #pragma unroll
    for (int e = 0; e < 4; ++e) {
      float p = acc2[rf][0][e] * acc2[rf][0][e] + acc2[rf][1][e] * acc2[rf][1][e];
      p += __shfl_xor(p, 1, 16); p += __shfl_xor(p, 2, 16);
      p += __shfl_xor(p, 4, 16); p += __shfl_xor(p, 8, 16);
      if (q == 0) s_red[(16 * rf + 4 * g + e) * 4 + wid] = p;
    }
  }
  __syncthreads();
  #pragma unroll
  for (int rf = 0; rf < 2; ++rf) {
    #pragma unroll
    for (int e = 0; e < 4; ++e) {
      int row = 16 * rf + 4 * g + e;
      float s = s_red[row * 4] + s_red[row * 4 + 1] + s_red[row * 4 + 2] + s_red[row * 4 + 3];
      float sc = 1.f / fmaxf(sqrtf(s), 1e-12f);
      #pragma unroll
      for (int cf = 0; cf < 2; ++cf)
        outp[(size_t)(i0 + row) * TD + wid * 32 + cf * 16 + q] = acc2[rf][cf][e] * sc;
    }
  }
}

// ======================= qt = gue @ WqkS + bqk =======================
__global__ __launch_bounds__(256) void qt_kernel(
    const float* __restrict__ gcn_user, const float* __restrict__ WqkS,
    const float* __restrict__ bqk, float* __restrict__ qt)
{
  __shared__ float s_gue[16 * 132];
  const int tid = threadIdx.x;
  const int u0 = blockIdx.x * 16;
  #pragma unroll
  for (int r = 0; r < 8; ++r) {
    int lin = r * 256 + tid;
    int u = lin >> 7, c = lin & 127;
    s_gue[u * 132 + c] = gcn_user[(size_t)(u0 + u) * GCN + c];
  }
  __syncthreads();
  const int ul = tid >> 4, tx = tid & 15, c0 = tx * 8;
  float a[8];
  { float4 b4 = *(const float4*)(bqk + c0); float4 b5 = *(const float4*)(bqk + c0 + 4);
    a[0]=b4.x; a[1]=b4.y; a[2]=b4.z; a[3]=b4.w; a[4]=b5.x; a[5]=b5.y; a[6]=b5.z; a[7]=b5.w; }
  for (int g = 0; g < 128; ++g) {
    float x = s_gue[ul * 132 + g];
    float4 w4 = *(const float4*)(WqkS + g * 128 + c0);
    float4 w5 = *(const float4*)(WqkS + g * 128 + c0 + 4);
    a[0] = fmaf(x, w4.x, a[0]); a[1] = fmaf(x, w4.y, a[1]);
    a[2] = fmaf(x, w4.z, a[2]); a[3] = fmaf(x, w4.w, a[3]);
    a[4] = fmaf(x, w5.x, a[4]); a[5] = fmaf(x, w5.y, a[5]);
    a[6] = fmaf(x, w5.z, a[6]); a[7] = fmaf(x, w5.w, a[7]);
  }
  float* op = qt + (size_t)(u0 + ul) * TD + c0;
  *(float4*)op = make_float4(a[0], a[1], a[2], a[3]);
  *(float4*)(op + 4) = make_float4(a[4], a[5], a[6], a[7]);
}

// ======================= attention: one wave per user, bf16 gather =======================
__global__ __launch_bounds__(256) void attn_kernel(
    const int* __restrict__ user_items, const float* __restrict__ qt,
    const ushort* __restrict__ itemB, ushort* __restrict__ repB)
{
  __shared__ int s_idx[4][52];
  const int tid = threadIdx.x;
  const int wid = tid >> 6, lane = tid & 63, g = lane >> 4, q = lane & 15;
  const int u = blockIdx.x * 4 + wid;
  const int c0 = q * 8;

  if (lane < 52) s_idx[wid][lane] = (lane < 50) ? user_items[(size_t)u * RK + lane] : 0;
  float qv[8];
  { float4 a = *(const float4*)(qt + (size_t)u * TD + c0);
    float4 b = *(const float4*)(qt + (size_t)u * TD + c0 + 4);
    qv[0]=a.x; qv[1]=a.y; qv[2]=a.z; qv[3]=a.w; qv[4]=b.x; qv[5]=b.y; qv[6]=b.z; qv[7]=b.w; }
  // s_idx is wave-local: no block barrier needed

  uint4 h[13]; float sc[13];
  #pragma unroll
  for (int i = 0; i < 13; ++i) {
    int j = 4 * i + g;
    int idx = s_idx[wid][j];
    h[i] = *(const uint4*)(itemB + (size_t)idx * TD + c0);
    float p = bflo(h[i].x) * qv[0] + bfhi(h[i].x) * qv[1]
            + bflo(h[i].y) * qv[2] + bfhi(h[i].y) * qv[3]
            + bflo(h[i].z) * qv[4] + bfhi(h[i].z) * qv[5]
            + bflo(h[i].w) * qv[6] + bfhi(h[i].w) * qv[7];
    p += __shfl_xor(p, 1, 16); p += __shfl_xor(p, 2, 16);
    p += __shfl_xor(p, 4, 16); p += __shfl_xor(p, 8, 16);
    sc[i] = (j < RK) ? p : -3.0e38f;
  }
  float m = sc[0];
  #pragma unroll
  for (int i = 1; i < 13; ++i) m = fmaxf(m, sc[i]);
  m = fmaxf(m, __shfl_xor(m, 16, 64));
  m = fmaxf(m, __shfl_xor(m, 32, 64));
  float ssum = 0.f;
  #pragma unroll
  for (int i = 0; i < 13; ++i) { sc[i] = __expf(sc[i] - m); ssum += sc[i]; }
  ssum += __shfl_xor(ssum, 16, 64);
  ssum += __shfl_xor(ssum, 32, 64);
  const float inv = 1.f / ssum;
  float rep[8] = {0, 0, 0, 0, 0, 0, 0, 0};
  #pragma unroll
  for (int i = 0; i < 13; ++i) {
    float a = sc[i] * inv;
    rep[0] = fmaf(a, bflo(h[i].x), rep[0]); rep[1] = fmaf(a, bfhi(h[i].x), rep[1]);
    rep[2] = fmaf(a, bflo(h[i].y), rep[2]); rep[3] = fmaf(a, bfhi(h[i].y), rep[3]);
    rep[4] = fmaf(a, bflo(h[i].z), rep[4]); rep[5] = fmaf(a, bfhi(h[i].z), rep[5]);
    rep[6] = fmaf(a, bflo(h[i].w), rep[6]); rep[7] = fmaf(a, bfhi(h[i].w), rep[7]);
  }
  #pragma unroll
  for (int c = 0; c < 8; ++c) {
    rep[c] += __shfl_xor(rep[c], 16, 64);
    rep[c] += __shfl_xor(rep[c], 32, 64);
  }
  if (g == 0) {
    uint4 o;
    o.x = packbf2(rep[0], rep[1]); o.y = packbf2(rep[2], rep[3]);
    o.z = packbf2(rep[4], rep[5]); o.w = packbf2(rep[6], rep[7]);
    *(uint4*)(repB + (size_t)u * TD + c0) = o;
  }
}

extern "C" void kernel_launch(void* const* d_in, const int* in_sizes, int n_in,
                              void* d_out, int out_size, void* d_ws, size_t ws_size,
                              hipStream_t stream) {
  const float* item_feat  = (const float*)d_in[0];
  const float* gcn_item   = (const float*)d_in[1];
  const float* gcn_user   = (const float*)d_in[2];
  const int*   user_items = (const int*)  d_in[3];
  const float* Wg  = (const float*)d_in[4];
  const float* bg  = (const float*)d_in[5];
  const float* Wi1 = (const float*)d_in[6];
  const float* bi1 = (const float*)d_in[7];
  const float* Wi2 = (const float*)d_in[8];
  const float* bi2 = (const float*)d_in[9];
  const float* Wq  = (const float*)d_in[10];
  const float* bq  = (const float*)d_in[11];
  const float* Wk  = (const float*)d_in[12];
  // d_in[13] = bk: softmax-invariant, dropped
  const float* Wu1 = (const float*)d_in[14];
  const float* bu1 = (const float*)d_in[15];
  const float* Wu2 = (const float*)d_in[16];
  const float* bu2 = (const float*)d_in[17];
  float* out = (float*)d_out;

  // workspace layout (bytes): ~64.2 MB total
  char* ws = (char*)d_ws;
  ushort* Wi1P   = (ushort*)(ws + 0);         // 5*256*32*2  =  81920
  ushort* Wi2P   = (ushort*)(ws + 81920);     // 8*128*32*2  =  65536
  ushort* Wu1P   = (ushort*)(ws + 147456);    // 8*256*32*2  = 131072
  ushort* Wu2P   = (ushort*)(ws + 278528);    // 8*128*32*2  =  65536
  float*  WqkS   = (float*) (ws + 344064);    // 128*128*4   =  65536
  float*  bqk    = (float*) (ws + 409600);    // 128*4       =    512
  float*  qtb    = (float*) (ws + 410112);    // 16384*128*4 = 8388608
  ushort* gitemT = (ushort*)(ws + 8798720);   // 100032*128*2 = 25608192
  ushort* itemB  = (ushort*)(ws + 34406912);  // 100000*128*2 = 25600000
  ushort* repB   = (ushort*)(ws + 60006912);  // 16384*128*2  = 4194304

  prep_all<<<6989, 256, 0, stream>>>(Wi1, Wi2, Wu1, Wu2, Wq, Wk, bq, gcn_item,
                                     Wi1P, Wi2P, Wu1P, Wu2P, WqkS, bqk, gitemT);
  item_mlp<<<(NITEMS + 63) / 64, 256, 0, stream>>>(
      gitemT, item_feat, Wg, bg, Wi1P, bi1, Wi2P, bi2, out, itemB);
  qt_kernel<<<NUSERS / 16, 256, 0, stream>>>(gcn_user, WqkS, bqk, qtb);
  attn_kernel<<<NUSERS / 4, 256, 0, stream>>>(user_items, qtb, itemB, repB);
  user_mlp<<<NUSERS / 32, 256, 0, stream>>>(
      gcn_user, repB, Wu1P, bu1, Wu2P, bu2, out + (size_t)NITEMS * TD);
}